// Round 16
// baseline (292.237 us; speedup 1.0000x reference)
//
#include <hip/hip_runtime.h>
#include <cstdint>
#include <cstddef>

typedef float v4f __attribute__((ext_vector_type(4)));
typedef float v2f __attribute__((ext_vector_type(2)));
typedef float v16f __attribute__((ext_vector_type(16)));
typedef short v8s __attribute__((ext_vector_type(8)));
typedef unsigned short v4u __attribute__((ext_vector_type(4)));

typedef unsigned short ubf;   // raw bf16 bits

#define NPTS 16384
#define CD   256
#define NBAT 4
#define NPB  4096

__device__ __forceinline__ float bf2f(ubf u) {
    union { unsigned u; float f; } c; c.u = ((unsigned)u) << 16; return c.f;
}
__device__ __forceinline__ ubf f2bf(float f) {
    union { float f; unsigned u; } c; c.f = f;
    unsigned u = c.u;
    u += 0x7fffu + ((u >> 16) & 1u);           // round-nearest-even
    return (ubf)(u >> 16);
}

// -------- fused pre-pass: weight transpose (blocks >= 4096) + point attention
__global__ __launch_bounds__(256) void k_pre(
    const float* __restrict__ low, float* __restrict__ xout,
    const float* __restrict__ bott, const float* __restrict__ qkv,
    const float* __restrict__ mlp, const float* __restrict__ fus,
    ubf* __restrict__ wt) {
    const int bid = blockIdx.x;
    if (bid < 4096) {
        // ---- Point_Attentation ----
        const int lane = threadIdx.x & 63;
        const int row  = bid * 4 + (threadIdx.x >> 6);
        const float* p = low + (size_t)row * CD + lane * 4;
        v4f v = *reinterpret_cast<const v4f*>(p);
        float d[4];
        float s = v[0] + v[1] + v[2] + v[3];
#pragma unroll
        for (int o = 32; o >= 1; o >>= 1) s += __shfl_xor(s, o);
        const float mean = s * (1.0f / 256.0f);
        float ss = 0.f;
#pragma unroll
        for (int i = 0; i < 4; ++i) { d[i] = v[i] - mean; ss += d[i] * d[i]; }
#pragma unroll
        for (int o = 32; o >= 1; o >>= 1) ss += __shfl_xor(ss, o);
        const float var = ss * (1.0f / 4095.0f);    // reference: /(n-1), n=4096
        const float dn  = 1.0f / (4.0f * (var + 1e-5f));
        v4f o;
#pragma unroll
        for (int i = 0; i < 4; ++i) {
            const float e   = d[i] * d[i] * dn + 0.5f;
            const float sig = 1.0f / (1.0f + __expf(-e));
            o[i] = v[i] * (1.0f + sig);
        }
        *reinterpret_cast<v4f*>(xout + (size_t)row * CD + lane * 4) = o;
        return;
    }
    // ---- weight transpose+convert: W[K][256] f32 -> WT[256][K] bf16 ----
    const int bid2 = bid - 4096;
    const int z = bid2 >> 7, r = bid2 & 127;
    const float* src; int K; size_t doff;
    if (z < 6)       { src = bott + (size_t)z * 65536;       K = 256; doff = (size_t)z * 65536; }
    else if (z < 9)  { src = qkv  + (size_t)(z - 6) * 65536; K = 256; doff = (size_t)z * 65536; }
    else if (z < 11) { src = mlp  + (size_t)(z - 9) * 65536; K = 256; doff = (size_t)z * 65536; }
    else             { src = fus;                            K = 512; doff = (size_t)11 * 65536; }
    const int kt = (r >> 3) * 32, nt = (r & 7) * 32;
    if (kt >= K) return;
    __shared__ ubf tile[32][33];
    const int tx = threadIdx.x & 31, ty = threadIdx.x >> 5;   // 32 x 8
#pragma unroll
    for (int i = 0; i < 4; ++i)
        tile[ty * 4 + i][tx] = f2bf(src[(size_t)(kt + ty * 4 + i) * 256 + nt + tx]);
    __syncthreads();
    ubf* dst = wt + doff;
#pragma unroll
    for (int i = 0; i < 4; ++i)
        dst[(size_t)(nt + ty * 4 + i) * K + kt + tx] = tile[tx][ty * 4 + i];
}

// ------- fused conv1 (3 bottlenecks) + q-projection from the LDS tile --------
// grid 256, block 256 (4 waves 2x2). Per block: 64-row tile. qproj reads xls
// directly (saves a 16.8MB global re-read + one dispatch).
__global__ __launch_bounds__(256) void k_conv1(
    float* __restrict__ xA, const ubf* __restrict__ wT,
    const float* __restrict__ bb, const float* __restrict__ bg,
    const float* __restrict__ bbe, const float* __restrict__ bm_,
    const float* __restrict__ bv,
    const float* __restrict__ qg, const float* __restrict__ qbe,
    const float* __restrict__ qm, const float* __restrict__ qv,
    ubf* __restrict__ qB) {
    __shared__ __attribute__((aligned(16))) float xls[64 * 256];  // 64KB
    __shared__ __attribute__((aligned(16))) ubf   yls[64 * 256];  // 32KB

    const int lane = threadIdx.x & 63;
    const int w    = threadIdx.x >> 6;
    const int wr = w >> 1, wc = w & 1;
    const int q15 = lane & 15, g = lane >> 4;
    const int bm = blockIdx.x * 64;

    {
        float* xsrcb = xA + (size_t)bm * 256;
#pragma unroll
        for (int it = 0; it < 16; ++it) {
            const int L4 = (it * 256 + w * 64) * 4;      // wave-uniform f32 base
            const int Ll = L4 + lane * 4;
            const int row = Ll >> 8, col = (Ll & 255) ^ ((row & 7) << 3);
            __builtin_amdgcn_global_load_lds(
                (const __attribute__((address_space(1))) unsigned*)(xsrcb + row * 256 + col),
                (__attribute__((address_space(3))) unsigned*)(xls + L4), 16, 0, 0);
        }
    }
    __syncthreads();

    const int r0l = wr * 32 + q15;
#pragma unroll 1
    for (int s = 0; s < 3; ++s) {
        const ubf* W0 = wT + (size_t)(2 * s) * 65536;
        const ubf* W1 = wT + (size_t)(2 * s + 1) * 65536;

        v4f acc[2][8];
#pragma unroll
        for (int i = 0; i < 2; ++i)
#pragma unroll
            for (int j = 0; j < 8; ++j)
#pragma unroll
                for (int r = 0; r < 4; ++r) acc[i][j][r] = 0.f;
        for (int ks = 0; ks < 8; ++ks) {
            const int k0 = ks * 32 + g * 8;
            v8s afr[2], bfr[8];
#pragma unroll
            for (int mi = 0; mi < 2; ++mi) {
                const int row = r0l + mi * 16;
                const float* ap = &xls[row * 256 + (k0 ^ ((row & 7) << 3))];
                v4f a = *reinterpret_cast<const v4f*>(ap);
                v4f b = *reinterpret_cast<const v4f*>(ap + 4);
                v8s t;
#pragma unroll
                for (int j = 0; j < 4; ++j) { t[j] = (short)f2bf(a[j]); t[j + 4] = (short)f2bf(b[j]); }
                afr[mi] = t;
            }
#pragma unroll
            for (int ni = 0; ni < 8; ++ni)
                bfr[ni] = *reinterpret_cast<const v8s*>(W0 + (size_t)(wc * 128 + ni * 16 + q15) * 256 + k0);
#pragma unroll
            for (int mi = 0; mi < 2; ++mi)
#pragma unroll
                for (int ni = 0; ni < 8; ++ni)
                    acc[mi][ni] = __builtin_amdgcn_mfma_f32_16x16x32_bf16(afr[mi], bfr[ni], acc[mi][ni], 0, 0, 0);
        }
#pragma unroll
        for (int ni = 0; ni < 8; ++ni) {
            const int col = wc * 128 + ni * 16 + q15;
            const float sc  = bg[2 * s * 256 + col] * rsqrtf(bv[2 * s * 256 + col] + 1e-3f);
            const float tc  = bbe[2 * s * 256 + col] - bm_[2 * s * 256 + col] * sc;
            const float bia = bb[2 * s * 256 + col];
#pragma unroll
            for (int mi = 0; mi < 2; ++mi)
#pragma unroll
                for (int r = 0; r < 4; ++r) {
                    const int row = wr * 32 + mi * 16 + g * 4 + r;
                    float z = fmaxf((acc[mi][ni][r] + bia) * sc + tc, 0.f);
                    yls[row * 256 + (col ^ ((row & 7) << 3))] = f2bf(z);
                }
        }
        __syncthreads();

#pragma unroll
        for (int i = 0; i < 2; ++i)
#pragma unroll
            for (int j = 0; j < 8; ++j)
#pragma unroll
                for (int r = 0; r < 4; ++r) acc[i][j][r] = 0.f;
        for (int ks = 0; ks < 8; ++ks) {
            const int k0 = ks * 32 + g * 8;
            v8s afr[2], bfr[8];
#pragma unroll
            for (int mi = 0; mi < 2; ++mi) {
                const int row = r0l + mi * 16;
                afr[mi] = *reinterpret_cast<const v8s*>(&yls[row * 256 + (k0 ^ ((row & 7) << 3))]);
            }
#pragma unroll
            for (int ni = 0; ni < 8; ++ni)
                bfr[ni] = *reinterpret_cast<const v8s*>(W1 + (size_t)(wc * 128 + ni * 16 + q15) * 256 + k0);
#pragma unroll
            for (int mi = 0; mi < 2; ++mi)
#pragma unroll
                for (int ni = 0; ni < 8; ++ni)
                    acc[mi][ni] = __builtin_amdgcn_mfma_f32_16x16x32_bf16(afr[mi], bfr[ni], acc[mi][ni], 0, 0, 0);
        }
#pragma unroll
        for (int ni = 0; ni < 8; ++ni) {
            const int col = wc * 128 + ni * 16 + q15;
            const int c1 = (2 * s + 1) * 256 + col;
            const float sc  = bg[c1] * rsqrtf(bv[c1] + 1e-3f);
            const float tc  = bbe[c1] - bm_[c1] * sc;
            const float bia = bb[c1];
#pragma unroll
            for (int mi = 0; mi < 2; ++mi)
#pragma unroll
                for (int r = 0; r < 4; ++r) {
                    const int row = wr * 32 + mi * 16 + g * 4 + r;
                    float z = fmaxf((acc[mi][ni][r] + bia) * sc + tc, 0.f);
                    xls[row * 256 + (col ^ ((row & 7) << 3))] += z;
                }
        }
        __syncthreads();
    }

    // ---- write xls back to xA (undo swizzle) ----
    {
        float* xdstb = xA + (size_t)bm * 256;
#pragma unroll
        for (int it = 0; it < 16; ++it) {
            const int Ll = (it * 256 + threadIdx.x) * 4;
            const int row = Ll >> 8, cl = Ll & 255;
            const int gcol = cl ^ ((row & 7) << 3);
            *reinterpret_cast<v4f*>(xdstb + row * 256 + gcol) =
                *reinterpret_cast<const v4f*>(xls + Ll);
        }
    }

    // ---- q projection from the LDS-resident tile: q = BN(xls @ Wq) ----
    {
        const ubf* WQ = wT + (size_t)6 * 65536;
        v4f acc[2][8];
#pragma unroll
        for (int i = 0; i < 2; ++i)
#pragma unroll
            for (int j = 0; j < 8; ++j)
#pragma unroll
                for (int r = 0; r < 4; ++r) acc[i][j][r] = 0.f;
        for (int ks = 0; ks < 8; ++ks) {
            const int k0 = ks * 32 + g * 8;
            v8s afr[2], bfr[8];
#pragma unroll
            for (int mi = 0; mi < 2; ++mi) {
                const int row = r0l + mi * 16;
                const float* ap = &xls[row * 256 + (k0 ^ ((row & 7) << 3))];
                v4f a = *reinterpret_cast<const v4f*>(ap);
                v4f b = *reinterpret_cast<const v4f*>(ap + 4);
                v8s t;
#pragma unroll
                for (int j = 0; j < 4; ++j) { t[j] = (short)f2bf(a[j]); t[j + 4] = (short)f2bf(b[j]); }
                afr[mi] = t;
            }
#pragma unroll
            for (int ni = 0; ni < 8; ++ni)
                bfr[ni] = *reinterpret_cast<const v8s*>(WQ + (size_t)(wc * 128 + ni * 16 + q15) * 256 + k0);
#pragma unroll
            for (int mi = 0; mi < 2; ++mi)
#pragma unroll
                for (int ni = 0; ni < 8; ++ni)
                    acc[mi][ni] = __builtin_amdgcn_mfma_f32_16x16x32_bf16(afr[mi], bfr[ni], acc[mi][ni], 0, 0, 0);
        }
#pragma unroll
        for (int ni = 0; ni < 8; ++ni) {
            const int col = wc * 128 + ni * 16 + q15;
            const float sc = qg[col] * rsqrtf(qv[col] + 1e-3f);
            const float tc = qbe[col] - qm[col] * sc;
#pragma unroll
            for (int mi = 0; mi < 2; ++mi)
#pragma unroll
                for (int r = 0; r < 4; ++r) {
                    const int row = bm + wr * 32 + mi * 16 + g * 4 + r;
                    qB[(size_t)row * CD + col] = f2bf(acc[mi][ni][r] * sc + tc);
                }
        }
    }
}

// ---------------- K/V projection: one dispatch, 512 blocks -------------------
// V written CHUNK-MAJOR: vT[b][chunk=key>>5][c][key&31].
__global__ __launch_bounds__(256) void k_kv(
    const float* __restrict__ fh, const ubf* __restrict__ wTq,
    const float* __restrict__ qg, const float* __restrict__ qbe,
    const float* __restrict__ qm, const float* __restrict__ qv,
    ubf* __restrict__ kB, ubf* __restrict__ vT) {
    const int m = 1 + (blockIdx.y >> 1);         // 1=k, 2=v
    const ubf* WT = wTq + m * 65536;
    const float* gamma = qg + m * 256;
    const float* beta  = qbe + m * 256;
    const float* bmean = qm + m * 256;
    const float* bvar  = qv + m * 256;

    const int lane = threadIdx.x & 63;
    const int w    = threadIdx.x >> 6;
    const int wr = w >> 1, wc = w & 1;
    const int q15 = lane & 15, g = lane >> 4;
    const int bm = blockIdx.x * 128, bn = (blockIdx.y & 1) * 128;
    const int r0 = bm + wr * 64 + q15;
    const int c0 = bn + wc * 64 + q15;

    v4f acc[4][4];
#pragma unroll
    for (int i = 0; i < 4; ++i)
#pragma unroll
        for (int j = 0; j < 4; ++j)
#pragma unroll
            for (int r = 0; r < 4; ++r) acc[i][j][r] = 0.f;

    for (int ks = 0; ks < 8; ++ks) {
        const int k0 = ks * 32 + g * 8;
        v8s afr[4], bfr[4];
#pragma unroll
        for (int mi = 0; mi < 4; ++mi) {
            const float* ap = fh + (size_t)(r0 + mi * 16) * CD + k0;
            v4f a = *reinterpret_cast<const v4f*>(ap);
            v4f b = *reinterpret_cast<const v4f*>(ap + 4);
            v8s t;
#pragma unroll
            for (int j = 0; j < 4; ++j) { t[j] = (short)f2bf(a[j]); t[j + 4] = (short)f2bf(b[j]); }
            afr[mi] = t;
        }
#pragma unroll
        for (int ni = 0; ni < 4; ++ni)
            bfr[ni] = *reinterpret_cast<const v8s*>(WT + (size_t)(c0 + ni * 16) * 256 + k0);
#pragma unroll
        for (int mi = 0; mi < 4; ++mi)
#pragma unroll
            for (int ni = 0; ni < 4; ++ni)
                acc[mi][ni] = __builtin_amdgcn_mfma_f32_16x16x32_bf16(afr[mi], bfr[ni], acc[mi][ni], 0, 0, 0);
    }

#pragma unroll
    for (int ni = 0; ni < 4; ++ni) {
        const int col = c0 + ni * 16;
        const float sc = gamma[col] * rsqrtf(bvar[col] + 1e-3f);
        const float tc = beta[col] - bmean[col] * sc;
#pragma unroll
        for (int mi = 0; mi < 4; ++mi) {
            if (m == 2) {
                const int row0 = bm + wr * 64 + mi * 16 + g * 4;
                v4u pk;
#pragma unroll
                for (int r = 0; r < 4; ++r) pk[r] = f2bf(acc[mi][ni][r] * sc + tc);
                const int bb = row0 >> 12, key = row0 & 4095;
                const int ch = key >> 5, kin = key & 31;
                *reinterpret_cast<v4u*>(vT + (size_t)bb * (CD * NPB)
                                           + (size_t)ch * (CD * 32) + col * 32 + kin) = pk;
            } else {
#pragma unroll
                for (int r = 0; r < 4; ++r) {
                    const int row = bm + wr * 64 + mi * 16 + g * 4 + r;
                    kB[(size_t)row * CD + col] = f2bf(acc[mi][ni][r] * sc + tc);
                }
            }
        }
    }
}

// ---- async stages (128-thread block, 2 waves) -------------------------------
__device__ __forceinline__ void stage_k32(const ubf* __restrict__ kg,
                                          ubf* kd, int wave, int lane) {
#pragma unroll
    for (int it = 0; it < 8; ++it) {
        const int Lb = it * 1024 + wave * 512;
        const int L  = Lb + lane * 8;
        const int key = L >> 8, c8 = (L & 255) ^ ((key & 7) << 3);
        __builtin_amdgcn_global_load_lds(
            (const __attribute__((address_space(1))) unsigned*)(kg + key * CD + c8),
            (__attribute__((address_space(3))) unsigned*)(kd + Lb), 16, 0, 0);
    }
}
__device__ __forceinline__ void stage_v40(const ubf* __restrict__ vchunk,
                                          ubf* vd, int wave, int lane) {
#pragma unroll
    for (int it = 0; it < 10; ++it) {
        const int e0b = wave * 5120 + it * 512;      // wave-uniform elem base
        const int e0  = e0b + lane * 8;
        const int c   = e0 / 40;
        const int k0  = e0 - c * 40;                 // 0,8,16,24,32
        const ubf* src = (k0 < 32) ? (vchunk + c * 32 + k0) : vchunk;
        __builtin_amdgcn_global_load_lds(
            (const __attribute__((address_space(1))) unsigned*)src,
            (__attribute__((address_space(3))) unsigned*)(vd + e0b), 16, 0, 0);
    }
}

// ---------------- flash attention: 32x32x16, K+V double-buffer ---------------
// 512 blocks x 128 thr (2 waves x 32 q-rows). Keys [half*2048,+2048) in 64
// chunks of 32. LDS = 2x16K (K) + 2x20K (V) + 5K (P) = 77KB -> 2 blocks/CU.
// ONE barrier per chunk: stage(kc+1 -> buf^1) issued BEFORE compute(buf);
// barrier at chunk end drains stages + read-completes buf (T3 2-phase).
__global__ __launch_bounds__(128, 1) void k_attn(const ubf* __restrict__ qb, const ubf* __restrict__ kb,
                                                 const ubf* __restrict__ vt,
                                                 ubf* __restrict__ o0, ubf* __restrict__ o1,
                                                 float* __restrict__ ml) {
    __shared__ __attribute__((aligned(16))) ubf kbuf[2][32 * 256];   // 2x16KB
    __shared__ __attribute__((aligned(16))) ubf vbuf[2][256 * 40];   // 2x20KB
    __shared__ __attribute__((aligned(16))) ubf pls[2 * 32 * 40];    // 5KB

    const int raw = blockIdx.x;                  // XCD swizzle: xcd = (b<<1)|half
    const int xcd = raw & 7, qt = raw >> 3;      // qt 0..63
    const int b = xcd >> 1, half = xcd & 1;

    const int wave = threadIdx.x >> 6, lane = threadIdx.x & 63;
    const int q31 = lane & 31, h = lane >> 5;

    // Q fragments: qf[ks] = Q[q31][ks*16 + h*8 .. +8]  (B-operand of K@Q^T)
    const ubf* qrow = qb + ((size_t)(b * NPB + qt * 64 + wave * 32 + q31)) * CD + h * 8;
    v8s qf[16];
#pragma unroll
    for (int ks = 0; ks < 16; ++ks) qf[ks] = *reinterpret_cast<const v8s*>(qrow + ks * 16);

    v16f oacc[8];
#pragma unroll
    for (int t = 0; t < 8; ++t)
#pragma unroll
        for (int r = 0; r < 16; ++r) oacc[t][r] = 0.f;
    float m_run = -3.0e38f, l_run = 0.f;

    const ubf* kgb = kb + ((size_t)(b * NPB) + half * 2048) * CD;
    const ubf* vgb = vt + (size_t)b * (CD * NPB) + (size_t)(half * 64) * (CD * 32);
    ubf* pw = pls + wave * (32 * 40);

    stage_k32(kgb, kbuf[0], wave, lane);
    stage_v40(vgb, vbuf[0], wave, lane);
    __syncthreads();                             // chunk 0 ready

    for (int kc = 0; kc < 64; ++kc) {
        const int cur = kc & 1;
        const ubf* kls = kbuf[cur];
        const ubf* vls = vbuf[cur];

        // stage chunk kc+1 into the alternate buffers; flies across this
        // whole chunk's compute, drained by the single barrier below.
        if (kc + 1 < 64) {
            stage_k32(kgb + (size_t)(kc + 1) * 32 * CD, kbuf[cur ^ 1], wave, lane);
            stage_v40(vgb + (size_t)(kc + 1) * (CD * 32), vbuf[cur ^ 1], wave, lane);
        }

        // S' = K_chunk @ Q^T : A-frag lane reads K[key=q31][ks*16 + h*8 ..]
        v16f sacc;
#pragma unroll
        for (int r = 0; r < 16; ++r) sacc[r] = 0.f;
#pragma unroll
        for (int ks = 0; ks < 16; ++ks) {
            v8s af = *reinterpret_cast<const v8s*>(
                &kls[q31 * 256 + ((ks * 16 + h * 8) ^ ((q31 & 7) << 3))]);
            sacc = __builtin_amdgcn_mfma_f32_32x32x16_bf16(af, qf[ks], sacc, 0, 0, 0);
        }

        // online softmax with defer-rescale (THR=8); lane owns q=q31, 16 keys
        float mloc = -3.0e38f;
#pragma unroll
        for (int r = 0; r < 16; ++r) {
            float x = sacc[r] * 0.0625f;
            sacc[r] = x;
            mloc = fmaxf(mloc, x);
        }
        mloc = fmaxf(mloc, __shfl_xor(mloc, 32));
        if (!__all(mloc <= m_run + 8.0f)) {
            const float mnew  = fmaxf(m_run, mloc);
            const float alpha = __expf(m_run - mnew);
            l_run *= alpha;
#pragma unroll
            for (int t = 0; t < 8; ++t)
#pragma unroll
                for (int r = 0; r < 16; ++r) oacc[t][r] *= alpha;
            m_run = mnew;
        }
        float lloc = 0.f;
#pragma unroll
        for (int r = 0; r < 16; ++r) {
            float p = __expf(sacc[r] - m_run);
            sacc[r] = p;
            lloc += p;
        }
        lloc += __shfl_xor(lloc, 32);
        l_run += lloc;

        // P -> LDS (bf16 trunc): reg 4G+r holds key = r + 8G + 4h for q31
#pragma unroll
        for (int G = 0; G < 4; ++G) {
            unsigned u0, u1, u2, u3;
            { union { float f; unsigned u; } c; c.f = sacc[4 * G + 0]; u0 = c.u; }
            { union { float f; unsigned u; } c; c.f = sacc[4 * G + 1]; u1 = c.u; }
            { union { float f; unsigned u; } c; c.f = sacc[4 * G + 2]; u2 = c.u; }
            { union { float f; unsigned u; } c; c.f = sacc[4 * G + 3]; u3 = c.u; }
            unsigned p01 = (u0 >> 16) | (u1 & 0xFFFF0000u);
            unsigned p23 = (u2 >> 16) | (u3 & 0xFFFF0000u);
            const int e = q31 * 40 + 8 * G + 4 * h;
            *reinterpret_cast<unsigned*>(&pw[e])     = p01;
            *reinterpret_cast<unsigned*>(&pw[e + 2]) = p23;
        }
        // O[c][q] += V^T_chunk @ P : B-frag = P[kb + h*8 ..][q31]
        v8s pb0 = *reinterpret_cast<const v8s*>(&pw[q31 * 40 + 0  + 8 * h]);
        v8s pb1 = *reinterpret_cast<const v8s*>(&pw[q31 * 40 + 16 + 8 * h]);
#pragma unroll
        for (int t = 0; t < 8; ++t) {
            const int crow = (t * 32 + q31) * 40;
            v8s av0 = *reinterpret_cast<const v8s*>(&vls[crow + 0  + 8 * h]);
            oacc[t] = __builtin_amdgcn_mfma_f32_32x32x16_bf16(av0, pb0, oacc[t], 0, 0, 0);
            v8s av1 = *reinterpret_cast<const v8s*>(&vls[crow + 16 + 8 * h]);
            oacc[t] = __builtin_amdgcn_mfma_f32_32x32x16_bf16(av1, pb1, oacc[t], 0, 0, 0);
        }

        __syncthreads();   // drains stages (vmcnt0) + all waves done reading cur
    }

    // epilogue: unnormalized partial O (bf16) + per-row (m, l)
    const int grow = b * NPB + qt * 64 + wave * 32 + q31;
    ubf* aor = (half ? o1 : o0) + (size_t)grow * CD;
#pragma unroll
    for (int t = 0; t < 8; ++t)
#pragma unroll
        for (int G = 0; G < 4; ++G) {
            v4u pk;
#pragma unroll
            for (int r = 0; r < 4; ++r) pk[r] = f2bf(oacc[t][4 * G + r]);
            *reinterpret_cast<v4u*>(aor + t * 32 + 8 * G + 4 * h) = pk;
        }
    if (h == 0) {
        v2f d; d[0] = m_run; d[1] = l_run;
        *reinterpret_cast<v2f*>(ml + (size_t)(half * NPTS + grow) * 2) = d;
    }
}

// ---------------- fused tail: merge+mlp1 -> mlp2 -> fusion (K=512) -----------
__global__ __launch_bounds__(256) void k_tail(
    const ubf* __restrict__ o0, const ubf* __restrict__ o1, const float* __restrict__ ml,
    const float* __restrict__ xA, const ubf* __restrict__ wT,
    const float* __restrict__ mg, const float* __restrict__ mbe,
    const float* __restrict__ mm, const float* __restrict__ mv,
    const float* __restrict__ fb, const float* __restrict__ fg,
    const float* __restrict__ fbe, const float* __restrict__ fm,
    const float* __restrict__ fv, float* __restrict__ out) {
    __shared__ __attribute__((aligned(16))) ubf yls[64 * 256];   // 32KB

    const int lane = threadIdx.x & 63;
    const int w    = threadIdx.x >> 6;
    const int wr = w >> 1, wc = w & 1;
    const int q15 = lane & 15, g = lane >> 4;
    const int bm = blockIdx.x * 64;
    const int r0l = wr * 32 + q15;

    const ubf* W9  = wT + (size_t)9 * 65536;
    const ubf* W10 = wT + (size_t)10 * 65536;
    const ubf* W11 = wT + (size_t)11 * 65536;

    v4f acc[2][8];

    float a0[2], a1[2];
#pragma unroll
    for (int mi = 0; mi < 2; ++mi) {
        const int row = bm + r0l + mi * 16;
        const float m0 = ml[2 * row],          l0 = ml[2 * row + 1];
        const float m1 = ml[2 * (NPTS + row)], l1 = ml[2 * (NPTS + row) + 1];
        const float mx = fmaxf(m0, m1);
        const float w0 = __expf(m0 - mx), w1 = __expf(m1 - mx);
        const float inv = 1.0f / (w0 * l0 + w1 * l1);
        a0[mi] = w0 * inv; a1[mi] = w1 * inv;
    }
#pragma unroll
    for (int i = 0; i < 2; ++i)
#pragma unroll
        for (int j = 0; j < 8; ++j)
#pragma unroll
            for (int r = 0; r < 4; ++r) acc[i][j][r] = 0.f;
    for (int ks = 0; ks < 8; ++ks) {
        const int k0 = ks * 32 + g * 8;
        v8s afr[2], bfr[8];
#pragma unroll
        for (int mi = 0; mi < 2; ++mi) {
            const int row = bm + r0l + mi * 16;
            v8s u0 = *reinterpret_cast<const v8s*>(o0 + (size_t)row * CD + k0);
            v8s u1 = *reinterpret_cast<const v8s*>(o1 + (size_t)row * CD + k0);
            v8s t;
#pragma unroll
            for (int j = 0; j < 8; ++j)
                t[j] = (short)f2bf(a0[mi] * bf2f((ubf)u0[j]) + a1[mi] * bf2f((ubf)u1[j]));
            afr[mi] = t;
        }
#pragma unroll
        for (int ni = 0; ni < 8; ++ni)
            bfr[ni] = *reinterpret_cast<const v8s*>(W9 + (size_t)(wc * 128 + ni * 16 + q15) * 256 + k0);
#pragma unroll
        for (int mi = 0; mi < 2; ++mi)
#pragma unroll
            for (int ni = 0; ni < 8; ++ni)
                acc[mi][ni] = __builtin_amdgcn_mfma_f32_16x16x32_bf16(afr[mi], bfr[ni], acc[mi][ni], 0, 0, 0);
    }
#pragma unroll
    for (int ni = 0; ni < 8; ++ni) {
        const int col = wc * 128 + ni * 16 + q15;
        const float sc = mg[col] * rsqrtf(mv[col] + 1e-3f);
        const float tc = mbe[col] - mm[col] * sc;
#pragma unroll
        for (int mi = 0; mi < 2; ++mi)
#pragma unroll
            for (int r = 0; r < 4; ++r) {
                const int row = wr * 32 + mi * 16 + g * 4 + r;
                float z = fmaxf(acc[mi][ni][r] * sc + tc, 0.f);
                yls[row * 256 + (col ^ ((row & 7) << 3))] = f2bf(z);
            }
    }
    __syncthreads();

#pragma unroll
    for (int i = 0; i < 2; ++i)
#pragma unroll
        for (int j = 0; j < 8; ++j)
#pragma unroll
            for (int r = 0; r < 4; ++r) acc[i][j][r] = 0.f;
    for (int ks = 0; ks < 8; ++ks) {
        const int k0 = ks * 32 + g * 8;
        v8s afr[2], bfr[8];
#pragma unroll
        for (int mi = 0; mi < 2; ++mi) {
            const int row = r0l + mi * 16;
            afr[mi] = *reinterpret_cast<const v8s*>(&yls[row * 256 + (k0 ^ ((row & 7) << 3))]);
        }
#pragma unroll
        for (int ni = 0; ni < 8; ++ni)
            bfr[ni] = *reinterpret_cast<const v8s*>(W10 + (size_t)(wc * 128 + ni * 16 + q15) * 256 + k0);
#pragma unroll
        for (int mi = 0; mi < 2; ++mi)
#pragma unroll
            for (int ni = 0; ni < 8; ++ni)
                acc[mi][ni] = __builtin_amdgcn_mfma_f32_16x16x32_bf16(afr[mi], bfr[ni], acc[mi][ni], 0, 0, 0);
    }
    __syncthreads();
#pragma unroll
    for (int ni = 0; ni < 8; ++ni) {
        const int col = wc * 128 + ni * 16 + q15;
        const float sc = mg[256 + col] * rsqrtf(mv[256 + col] + 1e-3f);
        const float tc = mbe[256 + col] - mm[256 + col] * sc;
#pragma unroll
        for (int mi = 0; mi < 2; ++mi)
#pragma unroll
            for (int r = 0; r < 4; ++r) {
                const int row = wr * 32 + mi * 16 + g * 4 + r;
                float z = fmaxf(acc[mi][ni][r] * sc + tc, 0.f);
                yls[row * 256 + (col ^ ((row & 7) << 3))] = f2bf(z);
            }
    }
    __syncthreads();

#pragma unroll
    for (int i = 0; i < 2; ++i)
#pragma unroll
        for (int j = 0; j < 8; ++j)
#pragma unroll
            for (int r = 0; r < 4; ++r) acc[i][j][r] = 0.f;
    for (int ks = 0; ks < 16; ++ks) {
        const int k0 = ks * 32 + g * 8;
        v8s afr[2], bfr[8];
#pragma unroll
        for (int mi = 0; mi < 2; ++mi) {
            if (k0 < 256) {
                const float* ap = xA + (size_t)(bm + r0l + mi * 16) * CD + k0;
                v4f a = *reinterpret_cast<const v4f*>(ap);
                v4f b = *reinterpret_cast<const v4f*>(ap + 4);
                v8s t;
#pragma unroll
                for (int j = 0; j < 4; ++j) { t[j] = (short)f2bf(a[j]); t[j + 4] = (short)f2bf(b[j]); }
                afr[mi] = t;
            } else {
                const int row = r0l + mi * 16, kk = k0 - 256;
                afr[mi] = *reinterpret_cast<const v8s*>(&yls[row * 256 + (kk ^ ((row & 7) << 3))]);
            }
        }
#pragma unroll
        for (int ni = 0; ni < 8; ++ni)
            bfr[ni] = *reinterpret_cast<const v8s*>(W11 + (size_t)(wc * 128 + ni * 16 + q15) * 512 + k0);
#pragma unroll
        for (int mi = 0; mi < 2; ++mi)
#pragma unroll
            for (int ni = 0; ni < 8; ++ni)
                acc[mi][ni] = __builtin_amdgcn_mfma_f32_16x16x32_bf16(afr[mi], bfr[ni], acc[mi][ni], 0, 0, 0);
    }
#pragma unroll
    for (int ni = 0; ni < 8; ++ni) {
        const int col = wc * 128 + ni * 16 + q15;
        const float sc = fg[col] * rsqrtf(fv[col] + 1e-3f);
        const float tc = fbe[col] - fm[col] * sc;
        const float bia = fb[col];
#pragma unroll
        for (int mi = 0; mi < 2; ++mi)
#pragma unroll
            for (int r = 0; r < 4; ++r) {
                const int row = bm + wr * 32 + mi * 16 + g * 4 + r;
                float z = fmaxf((acc[mi][ni][r] + bia) * sc + tc, 0.f);
                out[(size_t)row * CD + col] = z;
            }
    }
}

// ---------------- launcher ---------------------------------------------------
extern "C" void kernel_launch(void* const* d_in, const int* in_sizes, int n_in,
                              void* d_out, int out_size, void* d_ws, size_t ws_size,
                              hipStream_t stream) {
    const float* f_low   = (const float*)d_in[0];
    const float* f_high  = (const float*)d_in[1];
    const float* bott_W  = (const float*)d_in[2];
    const float* bott_b  = (const float*)d_in[3];
    const float* bott_g  = (const float*)d_in[4];
    const float* bott_be = (const float*)d_in[5];
    const float* bott_m  = (const float*)d_in[6];
    const float* bott_v  = (const float*)d_in[7];
    const float* qkv_W   = (const float*)d_in[8];
    const float* qkv_g   = (const float*)d_in[9];
    const float* qkv_be  = (const float*)d_in[10];
    const float* qkv_m   = (const float*)d_in[11];
    const float* qkv_v   = (const float*)d_in[12];
    const float* mlp_W   = (const float*)d_in[13];
    const float* mlp_g   = (const float*)d_in[14];
    const float* mlp_be  = (const float*)d_in[15];
    const float* mlp_m   = (const float*)d_in[16];
    const float* mlp_v   = (const float*)d_in[17];
    const float* fus_W   = (const float*)d_in[18];
    const float* fus_b   = (const float*)d_in[19];
    const float* fus_g   = (const float*)d_in[20];
    const float* fus_be  = (const float*)d_in[21];
    const float* fus_m   = (const float*)d_in[22];
    const float* fus_v   = (const float*)d_in[23];
    (void)in_sizes; (void)n_in; (void)out_size; (void)ws_size;

    char* ws = (char*)d_ws;
    const size_t MB = 1024 * 1024;
    float* xA = (float*)(ws);                       // 16.8 MB residual stream
    ubf*   o0 = (ubf*)  (ws + 17 * MB);             // 8.4 MB attn half0 partial
    ubf*   qB = (ubf*)  (ws + 26 * MB);             // 8.4 MB Q
    ubf*   kB = (ubf*)  (ws + 35 * MB);             // 8.4 MB K
    ubf*   vT = (ubf*)  (ws + 44 * MB);             // 8.4 MB V chunk-major
    ubf*   wT = (ubf*)  (ws + 53 * MB);             // 1.7 MB, 12 transposed weights
    ubf*   o1 = (ubf*)  (ws + 56 * MB);             // 8.4 MB attn half1 partial
    float* ml = (float*)(ws + 65 * MB);             // 512 KB (m,l) x 2 halves

    k_pre<<<dim3(4096 + 1536), dim3(256), 0, stream>>>(f_low, xA,
                                                       bott_W, qkv_W, mlp_W, fus_W, wT);

    k_kv<<<dim3(128, 4), dim3(256), 0, stream>>>(f_high, wT + (size_t)6 * 65536,
                                                 qkv_g, qkv_be, qkv_m, qkv_v, kB, vT);

    k_conv1<<<dim3(256), dim3(256), 0, stream>>>(xA, wT,
                                                 bott_b, bott_g, bott_be, bott_m, bott_v,
                                                 qkv_g, qkv_be, qkv_m, qkv_v, qB);

    k_attn<<<dim3(512), dim3(128), 0, stream>>>(qB, kB, vT, o0, o1, ml);

    k_tail<<<dim3(256), dim3(256), 0, stream>>>(o0, o1, ml, xA, wT,
                                                mlp_g, mlp_be, mlp_m, mlp_v,
                                                fus_b, fus_g, fus_be, fus_m, fus_v,
                                                (float*)d_out);
}

// Round 17
// 291.032 us; speedup vs baseline: 1.0041x; 1.0041x over previous
//
#include <hip/hip_runtime.h>
#include <cstdint>
#include <cstddef>

typedef float v4f __attribute__((ext_vector_type(4)));
typedef float v2f __attribute__((ext_vector_type(2)));
typedef float v16f __attribute__((ext_vector_type(16)));
typedef short v8s __attribute__((ext_vector_type(8)));
typedef unsigned short v4u __attribute__((ext_vector_type(4)));

typedef unsigned short ubf;   // raw bf16 bits

#define NPTS 16384
#define CD   256
#define NBAT 4
#define NPB  4096

__device__ __forceinline__ float bf2f(ubf u) {
    union { unsigned u; float f; } c; c.u = ((unsigned)u) << 16; return c.f;
}
__device__ __forceinline__ ubf f2bf(float f) {
    union { float f; unsigned u; } c; c.f = f;
    unsigned u = c.u;
    u += 0x7fffu + ((u >> 16) & 1u);           // round-nearest-even
    return (ubf)(u >> 16);
}

// -------- fused pre-pass: weight transpose (blocks >= 4096) + point attention
__global__ __launch_bounds__(256) void k_pre(
    const float* __restrict__ low, float* __restrict__ xout,
    const float* __restrict__ bott, const float* __restrict__ qkv,
    const float* __restrict__ mlp, const float* __restrict__ fus,
    ubf* __restrict__ wt) {
    const int bid = blockIdx.x;
    if (bid < 4096) {
        // ---- Point_Attentation ----
        const int lane = threadIdx.x & 63;
        const int row  = bid * 4 + (threadIdx.x >> 6);
        const float* p = low + (size_t)row * CD + lane * 4;
        v4f v = *reinterpret_cast<const v4f*>(p);
        float d[4];
        float s = v[0] + v[1] + v[2] + v[3];
#pragma unroll
        for (int o = 32; o >= 1; o >>= 1) s += __shfl_xor(s, o);
        const float mean = s * (1.0f / 256.0f);
        float ss = 0.f;
#pragma unroll
        for (int i = 0; i < 4; ++i) { d[i] = v[i] - mean; ss += d[i] * d[i]; }
#pragma unroll
        for (int o = 32; o >= 1; o >>= 1) ss += __shfl_xor(ss, o);
        const float var = ss * (1.0f / 4095.0f);    // reference: /(n-1), n=4096
        const float dn  = 1.0f / (4.0f * (var + 1e-5f));
        v4f o;
#pragma unroll
        for (int i = 0; i < 4; ++i) {
            const float e   = d[i] * d[i] * dn + 0.5f;
            const float sig = 1.0f / (1.0f + __expf(-e));
            o[i] = v[i] * (1.0f + sig);
        }
        *reinterpret_cast<v4f*>(xout + (size_t)row * CD + lane * 4) = o;
        return;
    }
    // ---- weight transpose+convert: W[K][256] f32 -> WT[256][K] bf16 ----
    const int bid2 = bid - 4096;
    const int z = bid2 >> 7, r = bid2 & 127;
    const float* src; int K; size_t doff;
    if (z < 6)       { src = bott + (size_t)z * 65536;       K = 256; doff = (size_t)z * 65536; }
    else if (z < 9)  { src = qkv  + (size_t)(z - 6) * 65536; K = 256; doff = (size_t)z * 65536; }
    else if (z < 11) { src = mlp  + (size_t)(z - 9) * 65536; K = 256; doff = (size_t)z * 65536; }
    else             { src = fus;                            K = 512; doff = (size_t)11 * 65536; }
    const int kt = (r >> 3) * 32, nt = (r & 7) * 32;
    if (kt >= K) return;
    __shared__ ubf tile[32][33];
    const int tx = threadIdx.x & 31, ty = threadIdx.x >> 5;   // 32 x 8
#pragma unroll
    for (int i = 0; i < 4; ++i)
        tile[ty * 4 + i][tx] = f2bf(src[(size_t)(kt + ty * 4 + i) * 256 + nt + tx]);
    __syncthreads();
    ubf* dst = wt + doff;
#pragma unroll
    for (int i = 0; i < 4; ++i)
        dst[(size_t)(nt + ty * 4 + i) * K + kt + tx] = tile[tx][ty * 4 + i];
}

// ------- fused conv1 (3 bottlenecks) + q-projection from the LDS tile --------
// qproj output is pre-scaled by 0.0625*log2(e) so attention softmax runs in
// exp2 domain with zero extra VALU.
__global__ __launch_bounds__(256) void k_conv1(
    float* __restrict__ xA, const ubf* __restrict__ wT,
    const float* __restrict__ bb, const float* __restrict__ bg,
    const float* __restrict__ bbe, const float* __restrict__ bm_,
    const float* __restrict__ bv,
    const float* __restrict__ qg, const float* __restrict__ qbe,
    const float* __restrict__ qm, const float* __restrict__ qv,
    ubf* __restrict__ qB) {
    __shared__ __attribute__((aligned(16))) float xls[64 * 256];  // 64KB
    __shared__ __attribute__((aligned(16))) ubf   yls[64 * 256];  // 32KB

    const int lane = threadIdx.x & 63;
    const int w    = threadIdx.x >> 6;
    const int wr = w >> 1, wc = w & 1;
    const int q15 = lane & 15, g = lane >> 4;
    const int bm = blockIdx.x * 64;

    {
        float* xsrcb = xA + (size_t)bm * 256;
#pragma unroll
        for (int it = 0; it < 16; ++it) {
            const int L4 = (it * 256 + w * 64) * 4;      // wave-uniform f32 base
            const int Ll = L4 + lane * 4;
            const int row = Ll >> 8, col = (Ll & 255) ^ ((row & 7) << 3);
            __builtin_amdgcn_global_load_lds(
                (const __attribute__((address_space(1))) unsigned*)(xsrcb + row * 256 + col),
                (__attribute__((address_space(3))) unsigned*)(xls + L4), 16, 0, 0);
        }
    }
    __syncthreads();

    const int r0l = wr * 32 + q15;
#pragma unroll 1
    for (int s = 0; s < 3; ++s) {
        const ubf* W0 = wT + (size_t)(2 * s) * 65536;
        const ubf* W1 = wT + (size_t)(2 * s + 1) * 65536;

        v4f acc[2][8];
#pragma unroll
        for (int i = 0; i < 2; ++i)
#pragma unroll
            for (int j = 0; j < 8; ++j)
#pragma unroll
                for (int r = 0; r < 4; ++r) acc[i][j][r] = 0.f;
        for (int ks = 0; ks < 8; ++ks) {
            const int k0 = ks * 32 + g * 8;
            v8s afr[2], bfr[8];
#pragma unroll
            for (int mi = 0; mi < 2; ++mi) {
                const int row = r0l + mi * 16;
                const float* ap = &xls[row * 256 + (k0 ^ ((row & 7) << 3))];
                v4f a = *reinterpret_cast<const v4f*>(ap);
                v4f b = *reinterpret_cast<const v4f*>(ap + 4);
                v8s t;
#pragma unroll
                for (int j = 0; j < 4; ++j) { t[j] = (short)f2bf(a[j]); t[j + 4] = (short)f2bf(b[j]); }
                afr[mi] = t;
            }
#pragma unroll
            for (int ni = 0; ni < 8; ++ni)
                bfr[ni] = *reinterpret_cast<const v8s*>(W0 + (size_t)(wc * 128 + ni * 16 + q15) * 256 + k0);
#pragma unroll
            for (int mi = 0; mi < 2; ++mi)
#pragma unroll
                for (int ni = 0; ni < 8; ++ni)
                    acc[mi][ni] = __builtin_amdgcn_mfma_f32_16x16x32_bf16(afr[mi], bfr[ni], acc[mi][ni], 0, 0, 0);
        }
#pragma unroll
        for (int ni = 0; ni < 8; ++ni) {
            const int col = wc * 128 + ni * 16 + q15;
            const float sc  = bg[2 * s * 256 + col] * rsqrtf(bv[2 * s * 256 + col] + 1e-3f);
            const float tc  = bbe[2 * s * 256 + col] - bm_[2 * s * 256 + col] * sc;
            const float bia = bb[2 * s * 256 + col];
#pragma unroll
            for (int mi = 0; mi < 2; ++mi)
#pragma unroll
                for (int r = 0; r < 4; ++r) {
                    const int row = wr * 32 + mi * 16 + g * 4 + r;
                    float z = fmaxf((acc[mi][ni][r] + bia) * sc + tc, 0.f);
                    yls[row * 256 + (col ^ ((row & 7) << 3))] = f2bf(z);
                }
        }
        __syncthreads();

#pragma unroll
        for (int i = 0; i < 2; ++i)
#pragma unroll
            for (int j = 0; j < 8; ++j)
#pragma unroll
                for (int r = 0; r < 4; ++r) acc[i][j][r] = 0.f;
        for (int ks = 0; ks < 8; ++ks) {
            const int k0 = ks * 32 + g * 8;
            v8s afr[2], bfr[8];
#pragma unroll
            for (int mi = 0; mi < 2; ++mi) {
                const int row = r0l + mi * 16;
                afr[mi] = *reinterpret_cast<const v8s*>(&yls[row * 256 + (k0 ^ ((row & 7) << 3))]);
            }
#pragma unroll
            for (int ni = 0; ni < 8; ++ni)
                bfr[ni] = *reinterpret_cast<const v8s*>(W1 + (size_t)(wc * 128 + ni * 16 + q15) * 256 + k0);
#pragma unroll
            for (int mi = 0; mi < 2; ++mi)
#pragma unroll
                for (int ni = 0; ni < 8; ++ni)
                    acc[mi][ni] = __builtin_amdgcn_mfma_f32_16x16x32_bf16(afr[mi], bfr[ni], acc[mi][ni], 0, 0, 0);
        }
#pragma unroll
        for (int ni = 0; ni < 8; ++ni) {
            const int col = wc * 128 + ni * 16 + q15;
            const int c1 = (2 * s + 1) * 256 + col;
            const float sc  = bg[c1] * rsqrtf(bv[c1] + 1e-3f);
            const float tc  = bbe[c1] - bm_[c1] * sc;
            const float bia = bb[c1];
#pragma unroll
            for (int mi = 0; mi < 2; ++mi)
#pragma unroll
                for (int r = 0; r < 4; ++r) {
                    const int row = wr * 32 + mi * 16 + g * 4 + r;
                    float z = fmaxf((acc[mi][ni][r] + bia) * sc + tc, 0.f);
                    xls[row * 256 + (col ^ ((row & 7) << 3))] += z;
                }
        }
        __syncthreads();
    }

    // ---- write xls back to xA (undo swizzle) ----
    {
        float* xdstb = xA + (size_t)bm * 256;
#pragma unroll
        for (int it = 0; it < 16; ++it) {
            const int Ll = (it * 256 + threadIdx.x) * 4;
            const int row = Ll >> 8, cl = Ll & 255;
            const int gcol = cl ^ ((row & 7) << 3);
            *reinterpret_cast<v4f*>(xdstb + row * 256 + gcol) =
                *reinterpret_cast<const v4f*>(xls + Ll);
        }
    }

    // ---- q projection from the LDS-resident tile (pre-scaled for exp2) ----
    {
        const ubf* WQ = wT + (size_t)6 * 65536;
        const float QSC = 0.0625f * 1.44269504f;     // fold scale + log2(e)
        v4f acc[2][8];
#pragma unroll
        for (int i = 0; i < 2; ++i)
#pragma unroll
            for (int j = 0; j < 8; ++j)
#pragma unroll
                for (int r = 0; r < 4; ++r) acc[i][j][r] = 0.f;
        for (int ks = 0; ks < 8; ++ks) {
            const int k0 = ks * 32 + g * 8;
            v8s afr[2], bfr[8];
#pragma unroll
            for (int mi = 0; mi < 2; ++mi) {
                const int row = r0l + mi * 16;
                const float* ap = &xls[row * 256 + (k0 ^ ((row & 7) << 3))];
                v4f a = *reinterpret_cast<const v4f*>(ap);
                v4f b = *reinterpret_cast<const v4f*>(ap + 4);
                v8s t;
#pragma unroll
                for (int j = 0; j < 4; ++j) { t[j] = (short)f2bf(a[j]); t[j + 4] = (short)f2bf(b[j]); }
                afr[mi] = t;
            }
#pragma unroll
            for (int ni = 0; ni < 8; ++ni)
                bfr[ni] = *reinterpret_cast<const v8s*>(WQ + (size_t)(wc * 128 + ni * 16 + q15) * 256 + k0);
#pragma unroll
            for (int mi = 0; mi < 2; ++mi)
#pragma unroll
                for (int ni = 0; ni < 8; ++ni)
                    acc[mi][ni] = __builtin_amdgcn_mfma_f32_16x16x32_bf16(afr[mi], bfr[ni], acc[mi][ni], 0, 0, 0);
        }
#pragma unroll
        for (int ni = 0; ni < 8; ++ni) {
            const int col = wc * 128 + ni * 16 + q15;
            const float sc = qg[col] * rsqrtf(qv[col] + 1e-3f) * QSC;
            const float tc = (qbe[col] - qm[col] * qg[col] * rsqrtf(qv[col] + 1e-3f)) * QSC;
#pragma unroll
            for (int mi = 0; mi < 2; ++mi)
#pragma unroll
                for (int r = 0; r < 4; ++r) {
                    const int row = bm + wr * 32 + mi * 16 + g * 4 + r;
                    qB[(size_t)row * CD + col] = f2bf(acc[mi][ni][r] * (sc / QSC) * QSC + tc);
                }
        }
    }
}

// ---------------- K/V projection: one dispatch, 512 blocks -------------------
// V written CHUNK-MAJOR: vT[b][chunk=key>>5][c][key&31].
__global__ __launch_bounds__(256) void k_kv(
    const float* __restrict__ fh, const ubf* __restrict__ wTq,
    const float* __restrict__ qg, const float* __restrict__ qbe,
    const float* __restrict__ qm, const float* __restrict__ qv,
    ubf* __restrict__ kB, ubf* __restrict__ vT) {
    const int m = 1 + (blockIdx.y >> 1);         // 1=k, 2=v
    const ubf* WT = wTq + m * 65536;
    const float* gamma = qg + m * 256;
    const float* beta  = qbe + m * 256;
    const float* bmean = qm + m * 256;
    const float* bvar  = qv + m * 256;

    const int lane = threadIdx.x & 63;
    const int w    = threadIdx.x >> 6;
    const int wr = w >> 1, wc = w & 1;
    const int q15 = lane & 15, g = lane >> 4;
    const int bm = blockIdx.x * 128, bn = (blockIdx.y & 1) * 128;
    const int r0 = bm + wr * 64 + q15;
    const int c0 = bn + wc * 64 + q15;

    v4f acc[4][4];
#pragma unroll
    for (int i = 0; i < 4; ++i)
#pragma unroll
        for (int j = 0; j < 4; ++j)
#pragma unroll
            for (int r = 0; r < 4; ++r) acc[i][j][r] = 0.f;

    for (int ks = 0; ks < 8; ++ks) {
        const int k0 = ks * 32 + g * 8;
        v8s afr[4], bfr[4];
#pragma unroll
        for (int mi = 0; mi < 4; ++mi) {
            const float* ap = fh + (size_t)(r0 + mi * 16) * CD + k0;
            v4f a = *reinterpret_cast<const v4f*>(ap);
            v4f b = *reinterpret_cast<const v4f*>(ap + 4);
            v8s t;
#pragma unroll
            for (int j = 0; j < 4; ++j) { t[j] = (short)f2bf(a[j]); t[j + 4] = (short)f2bf(b[j]); }
            afr[mi] = t;
        }
#pragma unroll
        for (int ni = 0; ni < 4; ++ni)
            bfr[ni] = *reinterpret_cast<const v8s*>(WT + (size_t)(c0 + ni * 16) * 256 + k0);
#pragma unroll
        for (int mi = 0; mi < 4; ++mi)
#pragma unroll
            for (int ni = 0; ni < 4; ++ni)
                acc[mi][ni] = __builtin_amdgcn_mfma_f32_16x16x32_bf16(afr[mi], bfr[ni], acc[mi][ni], 0, 0, 0);
    }

#pragma unroll
    for (int ni = 0; ni < 4; ++ni) {
        const int col = c0 + ni * 16;
        const float sc = gamma[col] * rsqrtf(bvar[col] + 1e-3f);
        const float tc = beta[col] - bmean[col] * sc;
#pragma unroll
        for (int mi = 0; mi < 4; ++mi) {
            if (m == 2) {
                const int row0 = bm + wr * 64 + mi * 16 + g * 4;
                v4u pk;
#pragma unroll
                for (int r = 0; r < 4; ++r) pk[r] = f2bf(acc[mi][ni][r] * sc + tc);
                const int bb = row0 >> 12, key = row0 & 4095;
                const int ch = key >> 5, kin = key & 31;
                *reinterpret_cast<v4u*>(vT + (size_t)bb * (CD * NPB)
                                           + (size_t)ch * (CD * 32) + col * 32 + kin) = pk;
            } else {
#pragma unroll
                for (int r = 0; r < 4; ++r) {
                    const int row = bm + wr * 64 + mi * 16 + g * 4 + r;
                    kB[(size_t)row * CD + col] = f2bf(acc[mi][ni][r] * sc + tc);
                }
            }
        }
    }
}

// ---- async stages (128-thread block, 2 waves) -------------------------------
__device__ __forceinline__ void stage_k32(const ubf* __restrict__ kg,
                                          ubf* kd, int wave, int lane) {
#pragma unroll
    for (int it = 0; it < 8; ++it) {
        const int Lb = it * 1024 + wave * 512;
        const int L  = Lb + lane * 8;
        const int key = L >> 8, c8 = (L & 255) ^ ((key & 7) << 3);
        __builtin_amdgcn_global_load_lds(
            (const __attribute__((address_space(1))) unsigned*)(kg + key * CD + c8),
            (__attribute__((address_space(3))) unsigned*)(kd + Lb), 16, 0, 0);
    }
}
__device__ __forceinline__ void stage_v40(const ubf* __restrict__ vchunk,
                                          ubf* vd, int wave, int lane) {
#pragma unroll
    for (int it = 0; it < 10; ++it) {
        const int e0b = wave * 5120 + it * 512;      // wave-uniform elem base
        const int e0  = e0b + lane * 8;
        const int c   = e0 / 40;
        const int k0  = e0 - c * 40;                 // 0,8,16,24,32
        const ubf* src = (k0 < 32) ? (vchunk + c * 32 + k0) : vchunk;
        __builtin_amdgcn_global_load_lds(
            (const __attribute__((address_space(1))) unsigned*)src,
            (__attribute__((address_space(3))) unsigned*)(vd + e0b), 16, 0, 0);
    }
}

// ---------------- flash attention: 32x32x16, r15 schedule + split QK chain ---
// 512 blocks x 128 thr (2 waves x 32 q-rows). Keys [half*2048,+2048) in 64
// chunks of 32. LDS = K 16K + V 20K + P 5K = 41KB (r15-proven, 2 blocks/CU).
// Schedule/chunk (r15): QK -> barrier -> stage K(kc+1) -> softmax+PV ->
// barrier -> stage V(kc+1). QK uses TWO independent accumulator chains
// (halved dependent-MFMA latency exposure). Softmax in exp2 domain (q was
// pre-scaled by 0.0625*log2e at projection).
__global__ __launch_bounds__(128, 1) void k_attn(const ubf* __restrict__ qb, const ubf* __restrict__ kb,
                                                 const ubf* __restrict__ vt,
                                                 ubf* __restrict__ o0, ubf* __restrict__ o1,
                                                 float* __restrict__ ml) {
    __shared__ __attribute__((aligned(16))) ubf kls[32 * 256];    // 16KB
    __shared__ __attribute__((aligned(16))) ubf vls[256 * 40];    // 20KB stride-40
    __shared__ __attribute__((aligned(16))) ubf pls[2 * 32 * 40]; // 5KB per-wave P

    const int raw = blockIdx.x;                  // XCD swizzle: xcd = (b<<1)|half
    const int xcd = raw & 7, qt = raw >> 3;      // qt 0..63
    const int b = xcd >> 1, half = xcd & 1;

    const int wave = threadIdx.x >> 6, lane = threadIdx.x & 63;
    const int q31 = lane & 31, h = lane >> 5;

    // Q fragments: qf[ks] = Q[q31][ks*16 + h*8 .. +8]  (B-operand of K@Q^T)
    const ubf* qrow = qb + ((size_t)(b * NPB + qt * 64 + wave * 32 + q31)) * CD + h * 8;
    v8s qf[16];
#pragma unroll
    for (int ks = 0; ks < 16; ++ks) qf[ks] = *reinterpret_cast<const v8s*>(qrow + ks * 16);

    v16f oacc[8];
#pragma unroll
    for (int t = 0; t < 8; ++t)
#pragma unroll
        for (int r = 0; r < 16; ++r) oacc[t][r] = 0.f;
    float m_run = -3.0e38f, l_run = 0.f;

    const ubf* kgb = kb + ((size_t)(b * NPB) + half * 2048) * CD;
    const ubf* vgb = vt + (size_t)b * (CD * NPB) + (size_t)(half * 64) * (CD * 32);
    ubf* pw = pls + wave * (32 * 40);

    stage_k32(kgb, kls, wave, lane);
    stage_v40(vgb, vls, wave, lane);
    __syncthreads();                             // chunk 0 ready

    for (int kc = 0; kc < 64; ++kc) {
        // S' = K_chunk @ Q^T with two independent MFMA chains
        v16f sa, sb;
#pragma unroll
        for (int r = 0; r < 16; ++r) { sa[r] = 0.f; sb[r] = 0.f; }
#pragma unroll
        for (int ks = 0; ks < 16; ks += 2) {
            v8s af0 = *reinterpret_cast<const v8s*>(
                &kls[q31 * 256 + (((ks    ) * 16 + h * 8) ^ ((q31 & 7) << 3))]);
            sa = __builtin_amdgcn_mfma_f32_32x32x16_bf16(af0, qf[ks],     sa, 0, 0, 0);
            v8s af1 = *reinterpret_cast<const v8s*>(
                &kls[q31 * 256 + (((ks + 1) * 16 + h * 8) ^ ((q31 & 7) << 3))]);
            sb = __builtin_amdgcn_mfma_f32_32x32x16_bf16(af1, qf[ks + 1], sb, 0, 0, 0);
        }

        __syncthreads();                         // kls reads done; V(kc) drained
        if (kc + 1 < 64)                         // K(kc+1) flies under softmax+PV
            stage_k32(kgb + (size_t)(kc + 1) * 32 * CD, kls, wave, lane);

        // online softmax, exp2 domain, defer-rescale (THR = 8*log2e = 11.54)
        v16f sacc;
        float mloc = -3.0e38f;
#pragma unroll
        for (int r = 0; r < 16; ++r) {
            float x = sa[r] + sb[r];
            sacc[r] = x;
            mloc = fmaxf(mloc, x);
        }
        mloc = fmaxf(mloc, __shfl_xor(mloc, 32));
        if (!__all(mloc <= m_run + 11.54f)) {
            const float mnew  = fmaxf(m_run, mloc);
            const float alpha = exp2f(m_run - mnew);
            l_run *= alpha;
#pragma unroll
            for (int t = 0; t < 8; ++t)
#pragma unroll
                for (int r = 0; r < 16; ++r) oacc[t][r] *= alpha;
            m_run = mnew;
        }
        float lloc = 0.f;
#pragma unroll
        for (int r = 0; r < 16; ++r) {
            float p = exp2f(sacc[r] - m_run);
            sacc[r] = p;
            lloc += p;
        }
        lloc += __shfl_xor(lloc, 32);
        l_run += lloc;

        // P -> LDS (bf16 trunc): reg 4G+r holds key = r + 8G + 4h for q31
#pragma unroll
        for (int G = 0; G < 4; ++G) {
            unsigned u0, u1, u2, u3;
            { union { float f; unsigned u; } c; c.f = sacc[4 * G + 0]; u0 = c.u; }
            { union { float f; unsigned u; } c; c.f = sacc[4 * G + 1]; u1 = c.u; }
            { union { float f; unsigned u; } c; c.f = sacc[4 * G + 2]; u2 = c.u; }
            { union { float f; unsigned u; } c; c.f = sacc[4 * G + 3]; u3 = c.u; }
            unsigned p01 = (u0 >> 16) | (u1 & 0xFFFF0000u);
            unsigned p23 = (u2 >> 16) | (u3 & 0xFFFF0000u);
            const int e = q31 * 40 + 8 * G + 4 * h;
            *reinterpret_cast<unsigned*>(&pw[e])     = p01;
            *reinterpret_cast<unsigned*>(&pw[e + 2]) = p23;
        }
        // O[c][q] += V^T_chunk @ P : B-frag = P[kb + h*8 ..][q31]
        v8s pb0 = *reinterpret_cast<const v8s*>(&pw[q31 * 40 + 0  + 8 * h]);
        v8s pb1 = *reinterpret_cast<const v8s*>(&pw[q31 * 40 + 16 + 8 * h]);
#pragma unroll
        for (int t = 0; t < 8; ++t) {
            const int crow = (t * 32 + q31) * 40;
            v8s av0 = *reinterpret_cast<const v8s*>(&vls[crow + 0  + 8 * h]);
            oacc[t] = __builtin_amdgcn_mfma_f32_32x32x16_bf16(av0, pb0, oacc[t], 0, 0, 0);
            v8s av1 = *reinterpret_cast<const v8s*>(&vls[crow + 16 + 8 * h]);
            oacc[t] = __builtin_amdgcn_mfma_f32_32x32x16_bf16(av1, pb1, oacc[t], 0, 0, 0);
        }

        __syncthreads();                         // vls reads done; K(kc+1) drained
        if (kc + 1 < 64)                         // V(kc+1) flies under next QK
            stage_v40(vgb + (size_t)(kc + 1) * (CD * 32), vls, wave, lane);
    }

    // epilogue: unnormalized partial O (bf16) + per-row (m, l); m in log2 dom.
    const int grow = b * NPB + qt * 64 + wave * 32 + q31;
    ubf* aor = (half ? o1 : o0) + (size_t)grow * CD;
#pragma unroll
    for (int t = 0; t < 8; ++t)
#pragma unroll
        for (int G = 0; G < 4; ++G) {
            v4u pk;
#pragma unroll
            for (int r = 0; r < 4; ++r) pk[r] = f2bf(oacc[t][4 * G + r]);
            *reinterpret_cast<v4u*>(aor + t * 32 + 8 * G + 4 * h) = pk;
        }
    if (h == 0) {
        v2f d; d[0] = m_run; d[1] = l_run;
        *reinterpret_cast<v2f*>(ml + (size_t)(half * NPTS + grow) * 2) = d;
    }
}

// ---------------- fused tail: merge+mlp1 -> mlp2 -> fusion (K=512) -----------
// NOTE: merge weights use exp2 (attention m is tracked in log2 domain).
__global__ __launch_bounds__(256) void k_tail(
    const ubf* __restrict__ o0, const ubf* __restrict__ o1, const float* __restrict__ ml,
    const float* __restrict__ xA, const ubf* __restrict__ wT,
    const float* __restrict__ mg, const float* __restrict__ mbe,
    const float* __restrict__ mm, const float* __restrict__ mv,
    const float* __restrict__ fb, const float* __restrict__ fg,
    const float* __restrict__ fbe, const float* __restrict__ fm,
    const float* __restrict__ fv, float* __restrict__ out) {
    __shared__ __attribute__((aligned(16))) ubf yls[64 * 256];   // 32KB

    const int lane = threadIdx.x & 63;
    const int w    = threadIdx.x >> 6;
    const int wr = w >> 1, wc = w & 1;
    const int q15 = lane & 15, g = lane >> 4;
    const int bm = blockIdx.x * 64;
    const int r0l = wr * 32 + q15;

    const ubf* W9  = wT + (size_t)9 * 65536;
    const ubf* W10 = wT + (size_t)10 * 65536;
    const ubf* W11 = wT + (size_t)11 * 65536;

    v4f acc[2][8];

    float a0[2], a1[2];
#pragma unroll
    for (int mi = 0; mi < 2; ++mi) {
        const int row = bm + r0l + mi * 16;
        const float m0 = ml[2 * row],          l0 = ml[2 * row + 1];
        const float m1 = ml[2 * (NPTS + row)], l1 = ml[2 * (NPTS + row) + 1];
        const float mx = fmaxf(m0, m1);
        const float w0 = exp2f(m0 - mx), w1 = exp2f(m1 - mx);
        const float inv = 1.0f / (w0 * l0 + w1 * l1);
        a0[mi] = w0 * inv; a1[mi] = w1 * inv;
    }
#pragma unroll
    for (int i = 0; i < 2; ++i)
#pragma unroll
        for (int j = 0; j < 8; ++j)
#pragma unroll
            for (int r = 0; r < 4; ++r) acc[i][j][r] = 0.f;
    for (int ks = 0; ks < 8; ++ks) {
        const int k0 = ks * 32 + g * 8;
        v8s afr[2], bfr[8];
#pragma unroll
        for (int mi = 0; mi < 2; ++mi) {
            const int row = bm + r0l + mi * 16;
            v8s u0 = *reinterpret_cast<const v8s*>(o0 + (size_t)row * CD + k0);
            v8s u1 = *reinterpret_cast<const v8s*>(o1 + (size_t)row * CD + k0);
            v8s t;
#pragma unroll
            for (int j = 0; j < 8; ++j)
                t[j] = (short)f2bf(a0[mi] * bf2f((ubf)u0[j]) + a1[mi] * bf2f((ubf)u1[j]));
            afr[mi] = t;
        }
#pragma unroll
        for (int ni = 0; ni < 8; ++ni)
            bfr[ni] = *reinterpret_cast<const v8s*>(W9 + (size_t)(wc * 128 + ni * 16 + q15) * 256 + k0);
#pragma unroll
        for (int mi = 0; mi < 2; ++mi)
#pragma unroll
            for (int ni = 0; ni < 8; ++ni)
                acc[mi][ni] = __builtin_amdgcn_mfma_f32_16x16x32_bf16(afr[mi], bfr[ni], acc[mi][ni], 0, 0, 0);
    }
#pragma unroll
    for (int ni = 0; ni < 8; ++ni) {
        const int col = wc * 128 + ni * 16 + q15;
        const float sc = mg[col] * rsqrtf(mv[col] + 1e-3f);
        const float tc = mbe[col] - mm[col] * sc;
#pragma unroll
        for (int mi = 0; mi < 2; ++mi)
#pragma unroll
            for (int r = 0; r < 4; ++r) {
                const int row = wr * 32 + mi * 16 + g * 4 + r;
                float z = fmaxf(acc[mi][ni][r] * sc + tc, 0.f);
                yls[row * 256 + (col ^ ((row & 7) << 3))] = f2bf(z);
            }
    }
    __syncthreads();

#pragma unroll
    for (int i = 0; i < 2; ++i)
#pragma unroll
        for (int j = 0; j < 8; ++j)
#pragma unroll
            for (int r = 0; r < 4; ++r) acc[i][j][r] = 0.f;
    for (int ks = 0; ks < 8; ++ks) {
        const int k0 = ks * 32 + g * 8;
        v8s afr[2], bfr[8];
#pragma unroll
        for (int mi = 0; mi < 2; ++mi) {
            const int row = r0l + mi * 16;
            afr[mi] = *reinterpret_cast<const v8s*>(&yls[row * 256 + (k0 ^ ((row & 7) << 3))]);
        }
#pragma unroll
        for (int ni = 0; ni < 8; ++ni)
            bfr[ni] = *reinterpret_cast<const v8s*>(W10 + (size_t)(wc * 128 + ni * 16 + q15) * 256 + k0);
#pragma unroll
        for (int mi = 0; mi < 2; ++mi)
#pragma unroll
            for (int ni = 0; ni < 8; ++ni)
                acc[mi][ni] = __builtin_amdgcn_mfma_f32_16x16x32_bf16(afr[mi], bfr[ni], acc[mi][ni], 0, 0, 0);
    }
    __syncthreads();
#pragma unroll
    for (int ni = 0; ni < 8; ++ni) {
        const int col = wc * 128 + ni * 16 + q15;
        const float sc = mg[256 + col] * rsqrtf(mv[256 + col] + 1e-3f);
        const float tc = mbe[256 + col] - mm[256 + col] * sc;
#pragma unroll
        for (int mi = 0; mi < 2; ++mi)
#pragma unroll
            for (int r = 0; r < 4; ++r) {
                const int row = wr * 32 + mi * 16 + g * 4 + r;
                float z = fmaxf(acc[mi][ni][r] * sc + tc, 0.f);
                yls[row * 256 + (col ^ ((row & 7) << 3))] = f2bf(z);
            }
    }
    __syncthreads();

#pragma unroll
    for (int i = 0; i < 2; ++i)
#pragma unroll
        for (int j = 0; j < 8; ++j)
#pragma unroll
            for (int r = 0; r < 4; ++r) acc[i][j][r] = 0.f;
    for (int ks = 0; ks < 16; ++ks) {
        const int k0 = ks * 32 + g * 8;
        v8s afr[2], bfr[8];
#pragma unroll
        for (int mi = 0; mi < 2; ++mi) {
            if (k0 < 256) {
                const float* ap = xA + (size_t)(bm + r0l + mi * 16) * CD + k0;
                v4f a = *reinterpret_cast<const v4f*>(ap);
                v4f b = *reinterpret_cast<const v4f*>(ap + 4);
                v8s t;
#pragma unroll
                for (int j = 0; j < 4; ++j) { t[j] = (short)f2bf(a[j]); t[j + 4] = (short)f2bf(b[j]); }
                afr[mi] = t;
            } else {
                const int row = r0l + mi * 16, kk = k0 - 256;
                afr[mi] = *reinterpret_cast<const v8s*>(&yls[row * 256 + (kk ^ ((row & 7) << 3))]);
            }
        }
#pragma unroll
        for (int ni = 0; ni < 8; ++ni)
            bfr[ni] = *reinterpret_cast<const v8s*>(W11 + (size_t)(wc * 128 + ni * 16 + q15) * 512 + k0);
#pragma unroll
        for (int mi = 0; mi < 2; ++mi)
#pragma unroll
            for (int ni = 0; ni < 8; ++ni)
                acc[mi][ni] = __builtin_amdgcn_mfma_f32_16x16x32_bf16(afr[mi], bfr[ni], acc[mi][ni], 0, 0, 0);
    }
#pragma unroll
    for (int ni = 0; ni < 8; ++ni) {
        const int col = wc * 128 + ni * 16 + q15;
        const float sc = fg[col] * rsqrtf(fv[col] + 1e-3f);
        const float tc = fbe[col] - fm[col] * sc;
        const float bia = fb[col];
#pragma unroll
        for (int mi = 0; mi < 2; ++mi)
#pragma unroll
            for (int r = 0; r < 4; ++r) {
                const int row = bm + wr * 32 + mi * 16 + g * 4 + r;
                float z = fmaxf((acc[mi][ni][r] + bia) * sc + tc, 0.f);
                out[(size_t)row * CD + col] = z;
            }
    }
}

// ---------------- launcher ---------------------------------------------------
extern "C" void kernel_launch(void* const* d_in, const int* in_sizes, int n_in,
                              void* d_out, int out_size, void* d_ws, size_t ws_size,
                              hipStream_t stream) {
    const float* f_low   = (const float*)d_in[0];
    const float* f_high  = (const float*)d_in[1];
    const float* bott_W  = (const float*)d_in[2];
    const float* bott_b  = (const float*)d_in[3];
    const float* bott_g  = (const float*)d_in[4];
    const float* bott_be = (const float*)d_in[5];
    const float* bott_m  = (const float*)d_in[6];
    const float* bott_v  = (const float*)d_in[7];
    const float* qkv_W   = (const float*)d_in[8];
    const float* qkv_g   = (const float*)d_in[9];
    const float* qkv_be  = (const float*)d_in[10];
    const float* qkv_m   = (const float*)d_in[11];
    const float* qkv_v   = (const float*)d_in[12];
    const float* mlp_W   = (const float*)d_in[13];
    const float* mlp_g   = (const float*)d_in[14];
    const float* mlp_be  = (const float*)d_in[15];
    const float* mlp_m   = (const float*)d_in[16];
    const float* mlp_v   = (const float*)d_in[17];
    const float* fus_W   = (const float*)d_in[18];
    const float* fus_b   = (const float*)d_in[19];
    const float* fus_g   = (const float*)d_in[20];
    const float* fus_be  = (const float*)d_in[21];
    const float* fus_m   = (const float*)d_in[22];
    const float* fus_v   = (const float*)d_in[23];
    (void)in_sizes; (void)n_in; (void)out_size; (void)ws_size;

    char* ws = (char*)d_ws;
    const size_t MB = 1024 * 1024;
    float* xA = (float*)(ws);                       // 16.8 MB residual stream
    ubf*   o0 = (ubf*)  (ws + 17 * MB);             // 8.4 MB attn half0 partial
    ubf*   qB = (ubf*)  (ws + 26 * MB);             // 8.4 MB Q (pre-scaled)
    ubf*   kB = (ubf*)  (ws + 35 * MB);             // 8.4 MB K
    ubf*   vT = (ubf*)  (ws + 44 * MB);             // 8.4 MB V chunk-major
    ubf*   wT = (ubf*)  (ws + 53 * MB);             // 1.7 MB, 12 transposed weights
    ubf*   o1 = (ubf*)  (ws + 56 * MB);             // 8.4 MB attn half1 partial
    float* ml = (float*)(ws + 65 * MB);             // 512 KB (m,l) x 2 halves

    k_pre<<<dim3(4096 + 1536), dim3(256), 0, stream>>>(f_low, xA,
                                                       bott_W, qkv_W, mlp_W, fus_W, wT);

    k_kv<<<dim3(128, 4), dim3(256), 0, stream>>>(f_high, wT + (size_t)6 * 65536,
                                                 qkv_g, qkv_be, qkv_m, qkv_v, kB, vT);

    k_conv1<<<dim3(256), dim3(256), 0, stream>>>(xA, wT,
                                                 bott_b, bott_g, bott_be, bott_m, bott_v,
                                                 qkv_g, qkv_be, qkv_m, qkv_v, qB);

    k_attn<<<dim3(512), dim3(128), 0, stream>>>(qB, kB, vT, o0, o1, ml);

    k_tail<<<dim3(256), dim3(256), 0, stream>>>(o0, o1, ml, xA, wT,
                                                mlp_g, mlp_be, mlp_m, mlp_v,
                                                fus_b, fus_g, fus_be, fus_m, fus_v,
                                                (float*)d_out);
}

// Round 18
// 289.827 us; speedup vs baseline: 1.0083x; 1.0042x over previous
//
#include <hip/hip_runtime.h>
#include <cstdint>
#include <cstddef>

typedef float v4f __attribute__((ext_vector_type(4)));
typedef float v2f __attribute__((ext_vector_type(2)));
typedef float v16f __attribute__((ext_vector_type(16)));
typedef short v8s __attribute__((ext_vector_type(8)));
typedef unsigned short v4u __attribute__((ext_vector_type(4)));

typedef unsigned short ubf;   // raw bf16 bits

#define NPTS 16384
#define CD   256
#define NBAT 4
#define NPB  4096

__device__ __forceinline__ float bf2f(ubf u) {
    union { unsigned u; float f; } c; c.u = ((unsigned)u) << 16; return c.f;
}
__device__ __forceinline__ ubf f2bf(float f) {
    union { float f; unsigned u; } c; c.f = f;
    unsigned u = c.u;
    u += 0x7fffu + ((u >> 16) & 1u);           // round-nearest-even
    return (ubf)(u >> 16);
}

// -------- fused pre-pass: weight transpose (blocks >= 4096) + point attention
__global__ __launch_bounds__(256) void k_pre(
    const float* __restrict__ low, float* __restrict__ xout,
    const float* __restrict__ bott, const float* __restrict__ qkv,
    const float* __restrict__ mlp, const float* __restrict__ fus,
    ubf* __restrict__ wt) {
    const int bid = blockIdx.x;
    if (bid < 4096) {
        // ---- Point_Attentation ----
        const int lane = threadIdx.x & 63;
        const int row  = bid * 4 + (threadIdx.x >> 6);
        const float* p = low + (size_t)row * CD + lane * 4;
        v4f v = *reinterpret_cast<const v4f*>(p);
        float d[4];
        float s = v[0] + v[1] + v[2] + v[3];
#pragma unroll
        for (int o = 32; o >= 1; o >>= 1) s += __shfl_xor(s, o);
        const float mean = s * (1.0f / 256.0f);
        float ss = 0.f;
#pragma unroll
        for (int i = 0; i < 4; ++i) { d[i] = v[i] - mean; ss += d[i] * d[i]; }
#pragma unroll
        for (int o = 32; o >= 1; o >>= 1) ss += __shfl_xor(ss, o);
        const float var = ss * (1.0f / 4095.0f);    // reference: /(n-1), n=4096
        const float dn  = 1.0f / (4.0f * (var + 1e-5f));
        v4f o;
#pragma unroll
        for (int i = 0; i < 4; ++i) {
            const float e   = d[i] * d[i] * dn + 0.5f;
            const float sig = 1.0f / (1.0f + __expf(-e));
            o[i] = v[i] * (1.0f + sig);
        }
        *reinterpret_cast<v4f*>(xout + (size_t)row * CD + lane * 4) = o;
        return;
    }
    // ---- weight transpose+convert: W[K][256] f32 -> WT[256][K] bf16 ----
    const int bid2 = bid - 4096;
    const int z = bid2 >> 7, r = bid2 & 127;
    const float* src; int K; size_t doff;
    if (z < 6)       { src = bott + (size_t)z * 65536;       K = 256; doff = (size_t)z * 65536; }
    else if (z < 9)  { src = qkv  + (size_t)(z - 6) * 65536; K = 256; doff = (size_t)z * 65536; }
    else if (z < 11) { src = mlp  + (size_t)(z - 9) * 65536; K = 256; doff = (size_t)z * 65536; }
    else             { src = fus;                            K = 512; doff = (size_t)11 * 65536; }
    const int kt = (r >> 3) * 32, nt = (r & 7) * 32;
    if (kt >= K) return;
    __shared__ ubf tile[32][33];
    const int tx = threadIdx.x & 31, ty = threadIdx.x >> 5;   // 32 x 8
#pragma unroll
    for (int i = 0; i < 4; ++i)
        tile[ty * 4 + i][tx] = f2bf(src[(size_t)(kt + ty * 4 + i) * 256 + nt + tx]);
    __syncthreads();
    ubf* dst = wt + doff;
#pragma unroll
    for (int i = 0; i < 4; ++i)
        dst[(size_t)(nt + ty * 4 + i) * K + kt + tx] = tile[tx][ty * 4 + i];
}

// ------- fused conv1 (3 bottlenecks) + q-projection from the LDS tile --------
// qproj output is pre-scaled by 0.0625*log2(e) so attention softmax runs in
// exp2 domain with zero extra VALU.
__global__ __launch_bounds__(256) void k_conv1(
    float* __restrict__ xA, const ubf* __restrict__ wT,
    const float* __restrict__ bb, const float* __restrict__ bg,
    const float* __restrict__ bbe, const float* __restrict__ bm_,
    const float* __restrict__ bv,
    const float* __restrict__ qg, const float* __restrict__ qbe,
    const float* __restrict__ qm, const float* __restrict__ qv,
    ubf* __restrict__ qB) {
    __shared__ __attribute__((aligned(16))) float xls[64 * 256];  // 64KB
    __shared__ __attribute__((aligned(16))) ubf   yls[64 * 256];  // 32KB

    const int lane = threadIdx.x & 63;
    const int w    = threadIdx.x >> 6;
    const int wr = w >> 1, wc = w & 1;
    const int q15 = lane & 15, g = lane >> 4;
    const int bm = blockIdx.x * 64;

    {
        float* xsrcb = xA + (size_t)bm * 256;
#pragma unroll
        for (int it = 0; it < 16; ++it) {
            const int L4 = (it * 256 + w * 64) * 4;      // wave-uniform f32 base
            const int Ll = L4 + lane * 4;
            const int row = Ll >> 8, col = (Ll & 255) ^ ((row & 7) << 3);
            __builtin_amdgcn_global_load_lds(
                (const __attribute__((address_space(1))) unsigned*)(xsrcb + row * 256 + col),
                (__attribute__((address_space(3))) unsigned*)(xls + L4), 16, 0, 0);
        }
    }
    __syncthreads();

    const int r0l = wr * 32 + q15;
#pragma unroll 1
    for (int s = 0; s < 3; ++s) {
        const ubf* W0 = wT + (size_t)(2 * s) * 65536;
        const ubf* W1 = wT + (size_t)(2 * s + 1) * 65536;

        v4f acc[2][8];
#pragma unroll
        for (int i = 0; i < 2; ++i)
#pragma unroll
            for (int j = 0; j < 8; ++j)
#pragma unroll
                for (int r = 0; r < 4; ++r) acc[i][j][r] = 0.f;
        for (int ks = 0; ks < 8; ++ks) {
            const int k0 = ks * 32 + g * 8;
            v8s afr[2], bfr[8];
#pragma unroll
            for (int mi = 0; mi < 2; ++mi) {
                const int row = r0l + mi * 16;
                const float* ap = &xls[row * 256 + (k0 ^ ((row & 7) << 3))];
                v4f a = *reinterpret_cast<const v4f*>(ap);
                v4f b = *reinterpret_cast<const v4f*>(ap + 4);
                v8s t;
#pragma unroll
                for (int j = 0; j < 4; ++j) { t[j] = (short)f2bf(a[j]); t[j + 4] = (short)f2bf(b[j]); }
                afr[mi] = t;
            }
#pragma unroll
            for (int ni = 0; ni < 8; ++ni)
                bfr[ni] = *reinterpret_cast<const v8s*>(W0 + (size_t)(wc * 128 + ni * 16 + q15) * 256 + k0);
#pragma unroll
            for (int mi = 0; mi < 2; ++mi)
#pragma unroll
                for (int ni = 0; ni < 8; ++ni)
                    acc[mi][ni] = __builtin_amdgcn_mfma_f32_16x16x32_bf16(afr[mi], bfr[ni], acc[mi][ni], 0, 0, 0);
        }
#pragma unroll
        for (int ni = 0; ni < 8; ++ni) {
            const int col = wc * 128 + ni * 16 + q15;
            const float sc  = bg[2 * s * 256 + col] * rsqrtf(bv[2 * s * 256 + col] + 1e-3f);
            const float tc  = bbe[2 * s * 256 + col] - bm_[2 * s * 256 + col] * sc;
            const float bia = bb[2 * s * 256 + col];
#pragma unroll
            for (int mi = 0; mi < 2; ++mi)
#pragma unroll
                for (int r = 0; r < 4; ++r) {
                    const int row = wr * 32 + mi * 16 + g * 4 + r;
                    float z = fmaxf((acc[mi][ni][r] + bia) * sc + tc, 0.f);
                    yls[row * 256 + (col ^ ((row & 7) << 3))] = f2bf(z);
                }
        }
        __syncthreads();

#pragma unroll
        for (int i = 0; i < 2; ++i)
#pragma unroll
            for (int j = 0; j < 8; ++j)
#pragma unroll
                for (int r = 0; r < 4; ++r) acc[i][j][r] = 0.f;
        for (int ks = 0; ks < 8; ++ks) {
            const int k0 = ks * 32 + g * 8;
            v8s afr[2], bfr[8];
#pragma unroll
            for (int mi = 0; mi < 2; ++mi) {
                const int row = r0l + mi * 16;
                afr[mi] = *reinterpret_cast<const v8s*>(&yls[row * 256 + (k0 ^ ((row & 7) << 3))]);
            }
#pragma unroll
            for (int ni = 0; ni < 8; ++ni)
                bfr[ni] = *reinterpret_cast<const v8s*>(W1 + (size_t)(wc * 128 + ni * 16 + q15) * 256 + k0);
#pragma unroll
            for (int mi = 0; mi < 2; ++mi)
#pragma unroll
                for (int ni = 0; ni < 8; ++ni)
                    acc[mi][ni] = __builtin_amdgcn_mfma_f32_16x16x32_bf16(afr[mi], bfr[ni], acc[mi][ni], 0, 0, 0);
        }
#pragma unroll
        for (int ni = 0; ni < 8; ++ni) {
            const int col = wc * 128 + ni * 16 + q15;
            const int c1 = (2 * s + 1) * 256 + col;
            const float sc  = bg[c1] * rsqrtf(bv[c1] + 1e-3f);
            const float tc  = bbe[c1] - bm_[c1] * sc;
            const float bia = bb[c1];
#pragma unroll
            for (int mi = 0; mi < 2; ++mi)
#pragma unroll
                for (int r = 0; r < 4; ++r) {
                    const int row = wr * 32 + mi * 16 + g * 4 + r;
                    float z = fmaxf((acc[mi][ni][r] + bia) * sc + tc, 0.f);
                    xls[row * 256 + (col ^ ((row & 7) << 3))] += z;
                }
        }
        __syncthreads();
    }

    // ---- write xls back to xA (undo swizzle) ----
    {
        float* xdstb = xA + (size_t)bm * 256;
#pragma unroll
        for (int it = 0; it < 16; ++it) {
            const int Ll = (it * 256 + threadIdx.x) * 4;
            const int row = Ll >> 8, cl = Ll & 255;
            const int gcol = cl ^ ((row & 7) << 3);
            *reinterpret_cast<v4f*>(xdstb + row * 256 + gcol) =
                *reinterpret_cast<const v4f*>(xls + Ll);
        }
    }

    // ---- q projection from the LDS-resident tile (pre-scaled for exp2) ----
    {
        const ubf* WQ = wT + (size_t)6 * 65536;
        const float QSC = 0.0625f * 1.44269504f;     // fold scale + log2(e)
        v4f acc[2][8];
#pragma unroll
        for (int i = 0; i < 2; ++i)
#pragma unroll
            for (int j = 0; j < 8; ++j)
#pragma unroll
                for (int r = 0; r < 4; ++r) acc[i][j][r] = 0.f;
        for (int ks = 0; ks < 8; ++ks) {
            const int k0 = ks * 32 + g * 8;
            v8s afr[2], bfr[8];
#pragma unroll
            for (int mi = 0; mi < 2; ++mi) {
                const int row = r0l + mi * 16;
                const float* ap = &xls[row * 256 + (k0 ^ ((row & 7) << 3))];
                v4f a = *reinterpret_cast<const v4f*>(ap);
                v4f b = *reinterpret_cast<const v4f*>(ap + 4);
                v8s t;
#pragma unroll
                for (int j = 0; j < 4; ++j) { t[j] = (short)f2bf(a[j]); t[j + 4] = (short)f2bf(b[j]); }
                afr[mi] = t;
            }
#pragma unroll
            for (int ni = 0; ni < 8; ++ni)
                bfr[ni] = *reinterpret_cast<const v8s*>(WQ + (size_t)(wc * 128 + ni * 16 + q15) * 256 + k0);
#pragma unroll
            for (int mi = 0; mi < 2; ++mi)
#pragma unroll
                for (int ni = 0; ni < 8; ++ni)
                    acc[mi][ni] = __builtin_amdgcn_mfma_f32_16x16x32_bf16(afr[mi], bfr[ni], acc[mi][ni], 0, 0, 0);
        }
#pragma unroll
        for (int ni = 0; ni < 8; ++ni) {
            const int col = wc * 128 + ni * 16 + q15;
            const float sc0 = qg[col] * rsqrtf(qv[col] + 1e-3f);
            const float sc  = sc0 * QSC;
            const float tc  = (qbe[col] - qm[col] * sc0) * QSC;
#pragma unroll
            for (int mi = 0; mi < 2; ++mi)
#pragma unroll
                for (int r = 0; r < 4; ++r) {
                    const int row = bm + wr * 32 + mi * 16 + g * 4 + r;
                    qB[(size_t)row * CD + col] = f2bf(acc[mi][ni][r] * sc + tc);
                }
        }
    }
}

// ---------------- K/V projection: one dispatch, 512 blocks -------------------
// V written CHUNK-MAJOR: vT[b][chunk=key>>5][c][key&31].
__global__ __launch_bounds__(256) void k_kv(
    const float* __restrict__ fh, const ubf* __restrict__ wTq,
    const float* __restrict__ qg, const float* __restrict__ qbe,
    const float* __restrict__ qm, const float* __restrict__ qv,
    ubf* __restrict__ kB, ubf* __restrict__ vT) {
    const int m = 1 + (blockIdx.y >> 1);         // 1=k, 2=v
    const ubf* WT = wTq + m * 65536;
    const float* gamma = qg + m * 256;
    const float* beta  = qbe + m * 256;
    const float* bmean = qm + m * 256;
    const float* bvar  = qv + m * 256;

    const int lane = threadIdx.x & 63;
    const int w    = threadIdx.x >> 6;
    const int wr = w >> 1, wc = w & 1;
    const int q15 = lane & 15, g = lane >> 4;
    const int bm = blockIdx.x * 128, bn = (blockIdx.y & 1) * 128;
    const int r0 = bm + wr * 64 + q15;
    const int c0 = bn + wc * 64 + q15;

    v4f acc[4][4];
#pragma unroll
    for (int i = 0; i < 4; ++i)
#pragma unroll
        for (int j = 0; j < 4; ++j)
#pragma unroll
            for (int r = 0; r < 4; ++r) acc[i][j][r] = 0.f;

    for (int ks = 0; ks < 8; ++ks) {
        const int k0 = ks * 32 + g * 8;
        v8s afr[4], bfr[4];
#pragma unroll
        for (int mi = 0; mi < 4; ++mi) {
            const float* ap = fh + (size_t)(r0 + mi * 16) * CD + k0;
            v4f a = *reinterpret_cast<const v4f*>(ap);
            v4f b = *reinterpret_cast<const v4f*>(ap + 4);
            v8s t;
#pragma unroll
            for (int j = 0; j < 4; ++j) { t[j] = (short)f2bf(a[j]); t[j + 4] = (short)f2bf(b[j]); }
            afr[mi] = t;
        }
#pragma unroll
        for (int ni = 0; ni < 4; ++ni)
            bfr[ni] = *reinterpret_cast<const v8s*>(WT + (size_t)(c0 + ni * 16) * 256 + k0);
#pragma unroll
        for (int mi = 0; mi < 4; ++mi)
#pragma unroll
            for (int ni = 0; ni < 4; ++ni)
                acc[mi][ni] = __builtin_amdgcn_mfma_f32_16x16x32_bf16(afr[mi], bfr[ni], acc[mi][ni], 0, 0, 0);
    }

#pragma unroll
    for (int ni = 0; ni < 4; ++ni) {
        const int col = c0 + ni * 16;
        const float sc = gamma[col] * rsqrtf(bvar[col] + 1e-3f);
        const float tc = beta[col] - bmean[col] * sc;
#pragma unroll
        for (int mi = 0; mi < 4; ++mi) {
            if (m == 2) {
                const int row0 = bm + wr * 64 + mi * 16 + g * 4;
                v4u pk;
#pragma unroll
                for (int r = 0; r < 4; ++r) pk[r] = f2bf(acc[mi][ni][r] * sc + tc);
                const int bb = row0 >> 12, key = row0 & 4095;
                const int ch = key >> 5, kin = key & 31;
                *reinterpret_cast<v4u*>(vT + (size_t)bb * (CD * NPB)
                                           + (size_t)ch * (CD * 32) + col * 32 + kin) = pk;
            } else {
#pragma unroll
                for (int r = 0; r < 4; ++r) {
                    const int row = bm + wr * 64 + mi * 16 + g * 4 + r;
                    kB[(size_t)row * CD + col] = f2bf(acc[mi][ni][r] * sc + tc);
                }
            }
        }
    }
}

// ---- async stages (128-thread block, 2 waves) -------------------------------
__device__ __forceinline__ void stage_k32(const ubf* __restrict__ kg,
                                          ubf* kd, int wave, int lane) {
#pragma unroll
    for (int it = 0; it < 8; ++it) {
        const int Lb = it * 1024 + wave * 512;
        const int L  = Lb + lane * 8;
        const int key = L >> 8, c8 = (L & 255) ^ ((key & 7) << 3);
        __builtin_amdgcn_global_load_lds(
            (const __attribute__((address_space(1))) unsigned*)(kg + key * CD + c8),
            (__attribute__((address_space(3))) unsigned*)(kd + Lb), 16, 0, 0);
    }
}
__device__ __forceinline__ void stage_v40(const ubf* __restrict__ vchunk,
                                          ubf* vd, int wave, int lane) {
#pragma unroll
    for (int it = 0; it < 10; ++it) {
        const int e0b = wave * 5120 + it * 512;      // wave-uniform elem base
        const int e0  = e0b + lane * 8;
        const int c   = e0 / 40;
        const int k0  = e0 - c * 40;                 // 0,8,16,24,32
        const ubf* src = (k0 < 32) ? (vchunk + c * 32 + k0) : vchunk;
        __builtin_amdgcn_global_load_lds(
            (const __attribute__((address_space(1))) unsigned*)src,
            (__attribute__((address_space(3))) unsigned*)(vd + e0b), 16, 0, 0);
    }
}

// ---------------- flash attention: 32x32x16, r15 schedule, exp2 softmax ------
// 512 blocks x 128 thr (2 waves x 32 q-rows). Keys [half*2048,+2048) in 64
// chunks of 32. LDS = K 16K + V 20K + P 5K = 41KB (r15-proven, 2 blocks/CU).
// Schedule/chunk (r15): QK -> barrier -> stage K(kc+1) -> softmax+PV ->
// barrier -> stage V(kc+1). Single QK accumulator chain (r17's split chain
// regressed: +27% VALU cycles, +8 VGPR). Softmax in exp2 domain (q pre-scaled
// by 0.0625*log2e at projection) — strictly fewer VALU ops than r15.
__global__ __launch_bounds__(128, 1) void k_attn(const ubf* __restrict__ qb, const ubf* __restrict__ kb,
                                                 const ubf* __restrict__ vt,
                                                 ubf* __restrict__ o0, ubf* __restrict__ o1,
                                                 float* __restrict__ ml) {
    __shared__ __attribute__((aligned(16))) ubf kls[32 * 256];    // 16KB
    __shared__ __attribute__((aligned(16))) ubf vls[256 * 40];    // 20KB stride-40
    __shared__ __attribute__((aligned(16))) ubf pls[2 * 32 * 40]; // 5KB per-wave P

    const int raw = blockIdx.x;                  // XCD swizzle: xcd = (b<<1)|half
    const int xcd = raw & 7, qt = raw >> 3;      // qt 0..63
    const int b = xcd >> 1, half = xcd & 1;

    const int wave = threadIdx.x >> 6, lane = threadIdx.x & 63;
    const int q31 = lane & 31, h = lane >> 5;

    // Q fragments: qf[ks] = Q[q31][ks*16 + h*8 .. +8]  (B-operand of K@Q^T)
    const ubf* qrow = qb + ((size_t)(b * NPB + qt * 64 + wave * 32 + q31)) * CD + h * 8;
    v8s qf[16];
#pragma unroll
    for (int ks = 0; ks < 16; ++ks) qf[ks] = *reinterpret_cast<const v8s*>(qrow + ks * 16);

    v16f oacc[8];
#pragma unroll
    for (int t = 0; t < 8; ++t)
#pragma unroll
        for (int r = 0; r < 16; ++r) oacc[t][r] = 0.f;
    float m_run = -3.0e38f, l_run = 0.f;

    const ubf* kgb = kb + ((size_t)(b * NPB) + half * 2048) * CD;
    const ubf* vgb = vt + (size_t)b * (CD * NPB) + (size_t)(half * 64) * (CD * 32);
    ubf* pw = pls + wave * (32 * 40);

    stage_k32(kgb, kls, wave, lane);
    stage_v40(vgb, vls, wave, lane);
    __syncthreads();                             // chunk 0 ready

    for (int kc = 0; kc < 64; ++kc) {
        // S' = K_chunk @ Q^T : A-frag lane reads K[key=q31][ks*16 + h*8 ..]
        v16f sacc;
#pragma unroll
        for (int r = 0; r < 16; ++r) sacc[r] = 0.f;
#pragma unroll
        for (int ks = 0; ks < 16; ++ks) {
            v8s af = *reinterpret_cast<const v8s*>(
                &kls[q31 * 256 + ((ks * 16 + h * 8) ^ ((q31 & 7) << 3))]);
            sacc = __builtin_amdgcn_mfma_f32_32x32x16_bf16(af, qf[ks], sacc, 0, 0, 0);
        }

        __syncthreads();                         // kls reads done; V(kc) drained
        if (kc + 1 < 64)                         // K(kc+1) flies under softmax+PV
            stage_k32(kgb + (size_t)(kc + 1) * 32 * CD, kls, wave, lane);

        // online softmax, exp2 domain, defer-rescale (THR = 8*log2e = 11.54)
        float mloc = -3.0e38f;
#pragma unroll
        for (int r = 0; r < 16; ++r) mloc = fmaxf(mloc, sacc[r]);
        mloc = fmaxf(mloc, __shfl_xor(mloc, 32));
        if (!__all(mloc <= m_run + 11.54f)) {
            const float mnew  = fmaxf(m_run, mloc);
            const float alpha = exp2f(m_run - mnew);
            l_run *= alpha;
#pragma unroll
            for (int t = 0; t < 8; ++t)
#pragma unroll
                for (int r = 0; r < 16; ++r) oacc[t][r] *= alpha;
            m_run = mnew;
        }
        float lloc = 0.f;
#pragma unroll
        for (int r = 0; r < 16; ++r) {
            float p = exp2f(sacc[r] - m_run);
            sacc[r] = p;
            lloc += p;
        }
        lloc += __shfl_xor(lloc, 32);
        l_run += lloc;

        // P -> LDS (bf16 trunc): reg 4G+r holds key = r + 8G + 4h for q31
#pragma unroll
        for (int G = 0; G < 4; ++G) {
            unsigned u0, u1, u2, u3;
            { union { float f; unsigned u; } c; c.f = sacc[4 * G + 0]; u0 = c.u; }
            { union { float f; unsigned u; } c; c.f = sacc[4 * G + 1]; u1 = c.u; }
            { union { float f; unsigned u; } c; c.f = sacc[4 * G + 2]; u2 = c.u; }
            { union { float f; unsigned u; } c; c.f = sacc[4 * G + 3]; u3 = c.u; }
            unsigned p01 = (u0 >> 16) | (u1 & 0xFFFF0000u);
            unsigned p23 = (u2 >> 16) | (u3 & 0xFFFF0000u);
            const int e = q31 * 40 + 8 * G + 4 * h;
            *reinterpret_cast<unsigned*>(&pw[e])     = p01;
            *reinterpret_cast<unsigned*>(&pw[e + 2]) = p23;
        }
        // O[c][q] += V^T_chunk @ P : B-frag = P[kb + h*8 ..][q31]
        v8s pb0 = *reinterpret_cast<const v8s*>(&pw[q31 * 40 + 0  + 8 * h]);
        v8s pb1 = *reinterpret_cast<const v8s*>(&pw[q31 * 40 + 16 + 8 * h]);
#pragma unroll
        for (int t = 0; t < 8; ++t) {
            const int crow = (t * 32 + q31) * 40;
            v8s av0 = *reinterpret_cast<const v8s*>(&vls[crow + 0  + 8 * h]);
            oacc[t] = __builtin_amdgcn_mfma_f32_32x32x16_bf16(av0, pb0, oacc[t], 0, 0, 0);
            v8s av1 = *reinterpret_cast<const v8s*>(&vls[crow + 16 + 8 * h]);
            oacc[t] = __builtin_amdgcn_mfma_f32_32x32x16_bf16(av1, pb1, oacc[t], 0, 0, 0);
        }

        __syncthreads();                         // vls reads done; K(kc+1) drained
        if (kc + 1 < 64)                         // V(kc+1) flies under next QK
            stage_v40(vgb + (size_t)(kc + 1) * (CD * 32), vls, wave, lane);
    }

    // epilogue: unnormalized partial O (bf16) + per-row (m, l); m in log2 dom.
    const int grow = b * NPB + qt * 64 + wave * 32 + q31;
    ubf* aor = (half ? o1 : o0) + (size_t)grow * CD;
#pragma unroll
    for (int t = 0; t < 8; ++t)
#pragma unroll
        for (int G = 0; G < 4; ++G) {
            v4u pk;
#pragma unroll
            for (int r = 0; r < 4; ++r) pk[r] = f2bf(oacc[t][4 * G + r]);
            *reinterpret_cast<v4u*>(aor + t * 32 + 8 * G + 4 * h) = pk;
        }
    if (h == 0) {
        v2f d; d[0] = m_run; d[1] = l_run;
        *reinterpret_cast<v2f*>(ml + (size_t)(half * NPTS + grow) * 2) = d;
    }
}

// ---------------- fused tail: merge+mlp1 -> mlp2 -> fusion (K=512) -----------
// NOTE: merge weights use exp2 (attention m is tracked in log2 domain).
__global__ __launch_bounds__(256) void k_tail(
    const ubf* __restrict__ o0, const ubf* __restrict__ o1, const float* __restrict__ ml,
    const float* __restrict__ xA, const ubf* __restrict__ wT,
    const float* __restrict__ mg, const float* __restrict__ mbe,
    const float* __restrict__ mm, const float* __restrict__ mv,
    const float* __restrict__ fb, const float* __restrict__ fg,
    const float* __restrict__ fbe, const float* __restrict__ fm,
    const float* __restrict__ fv, float* __restrict__ out) {
    __shared__ __attribute__((aligned(16))) ubf yls[64 * 256];   // 32KB

    const int lane = threadIdx.x & 63;
    const int w    = threadIdx.x >> 6;
    const int wr = w >> 1, wc = w & 1;
    const int q15 = lane & 15, g = lane >> 4;
    const int bm = blockIdx.x * 64;
    const int r0l = wr * 32 + q15;

    const ubf* W9  = wT + (size_t)9 * 65536;
    const ubf* W10 = wT + (size_t)10 * 65536;
    const ubf* W11 = wT + (size_t)11 * 65536;

    v4f acc[2][8];

    float a0[2], a1[2];
#pragma unroll
    for (int mi = 0; mi < 2; ++mi) {
        const int row = bm + r0l + mi * 16;
        const float m0 = ml[2 * row],          l0 = ml[2 * row + 1];
        const float m1 = ml[2 * (NPTS + row)], l1 = ml[2 * (NPTS + row) + 1];
        const float mx = fmaxf(m0, m1);
        const float w0 = exp2f(m0 - mx), w1 = exp2f(m1 - mx);
        const float inv = 1.0f / (w0 * l0 + w1 * l1);
        a0[mi] = w0 * inv; a1[mi] = w1 * inv;
    }
#pragma unroll
    for (int i = 0; i < 2; ++i)
#pragma unroll
        for (int j = 0; j < 8; ++j)
#pragma unroll
            for (int r = 0; r < 4; ++r) acc[i][j][r] = 0.f;
    for (int ks = 0; ks < 8; ++ks) {
        const int k0 = ks * 32 + g * 8;
        v8s afr[2], bfr[8];
#pragma unroll
        for (int mi = 0; mi < 2; ++mi) {
            const int row = bm + r0l + mi * 16;
            v8s u0 = *reinterpret_cast<const v8s*>(o0 + (size_t)row * CD + k0);
            v8s u1 = *reinterpret_cast<const v8s*>(o1 + (size_t)row * CD + k0);
            v8s t;
#pragma unroll
            for (int j = 0; j < 8; ++j)
                t[j] = (short)f2bf(a0[mi] * bf2f((ubf)u0[j]) + a1[mi] * bf2f((ubf)u1[j]));
            afr[mi] = t;
        }
#pragma unroll
        for (int ni = 0; ni < 8; ++ni)
            bfr[ni] = *reinterpret_cast<const v8s*>(W9 + (size_t)(wc * 128 + ni * 16 + q15) * 256 + k0);
#pragma unroll
        for (int mi = 0; mi < 2; ++mi)
#pragma unroll
            for (int ni = 0; ni < 8; ++ni)
                acc[mi][ni] = __builtin_amdgcn_mfma_f32_16x16x32_bf16(afr[mi], bfr[ni], acc[mi][ni], 0, 0, 0);
    }
#pragma unroll
    for (int ni = 0; ni < 8; ++ni) {
        const int col = wc * 128 + ni * 16 + q15;
        const float sc = mg[col] * rsqrtf(mv[col] + 1e-3f);
        const float tc = mbe[col] - mm[col] * sc;
#pragma unroll
        for (int mi = 0; mi < 2; ++mi)
#pragma unroll
            for (int r = 0; r < 4; ++r) {
                const int row = wr * 32 + mi * 16 + g * 4 + r;
                float z = fmaxf(acc[mi][ni][r] * sc + tc, 0.f);
                yls[row * 256 + (col ^ ((row & 7) << 3))] = f2bf(z);
            }
    }
    __syncthreads();

#pragma unroll
    for (int i = 0; i < 2; ++i)
#pragma unroll
        for (int j = 0; j < 8; ++j)
#pragma unroll
            for (int r = 0; r < 4; ++r) acc[i][j][r] = 0.f;
    for (int ks = 0; ks < 8; ++ks) {
        const int k0 = ks * 32 + g * 8;
        v8s afr[2], bfr[8];
#pragma unroll
        for (int mi = 0; mi < 2; ++mi) {
            const int row = r0l + mi * 16;
            afr[mi] = *reinterpret_cast<const v8s*>(&yls[row * 256 + (k0 ^ ((row & 7) << 3))]);
        }
#pragma unroll
        for (int ni = 0; ni < 8; ++ni)
            bfr[ni] = *reinterpret_cast<const v8s*>(W10 + (size_t)(wc * 128 + ni * 16 + q15) * 256 + k0);
#pragma unroll
        for (int mi = 0; mi < 2; ++mi)
#pragma unroll
            for (int ni = 0; ni < 8; ++ni)
                acc[mi][ni] = __builtin_amdgcn_mfma_f32_16x16x32_bf16(afr[mi], bfr[ni], acc[mi][ni], 0, 0, 0);
    }
    __syncthreads();
#pragma unroll
    for (int ni = 0; ni < 8; ++ni) {
        const int col = wc * 128 + ni * 16 + q15;
        const float sc = mg[256 + col] * rsqrtf(mv[256 + col] + 1e-3f);
        const float tc = mbe[256 + col] - mm[256 + col] * sc;
#pragma unroll
        for (int mi = 0; mi < 2; ++mi)
#pragma unroll
            for (int r = 0; r < 4; ++r) {
                const int row = wr * 32 + mi * 16 + g * 4 + r;
                float z = fmaxf(acc[mi][ni][r] * sc + tc, 0.f);
                yls[row * 256 + (col ^ ((row & 7) << 3))] = f2bf(z);
            }
    }
    __syncthreads();

#pragma unroll
    for (int i = 0; i < 2; ++i)
#pragma unroll
        for (int j = 0; j < 8; ++j)
#pragma unroll
            for (int r = 0; r < 4; ++r) acc[i][j][r] = 0.f;
    for (int ks = 0; ks < 16; ++ks) {
        const int k0 = ks * 32 + g * 8;
        v8s afr[2], bfr[8];
#pragma unroll
        for (int mi = 0; mi < 2; ++mi) {
            if (k0 < 256) {
                const float* ap = xA + (size_t)(bm + r0l + mi * 16) * CD + k0;
                v4f a = *reinterpret_cast<const v4f*>(ap);
                v4f b = *reinterpret_cast<const v4f*>(ap + 4);
                v8s t;
#pragma unroll
                for (int j = 0; j < 4; ++j) { t[j] = (short)f2bf(a[j]); t[j + 4] = (short)f2bf(b[j]); }
                afr[mi] = t;
            } else {
                const int row = r0l + mi * 16, kk = k0 - 256;
                afr[mi] = *reinterpret_cast<const v8s*>(&yls[row * 256 + (kk ^ ((row & 7) << 3))]);
            }
        }
#pragma unroll
        for (int ni = 0; ni < 8; ++ni)
            bfr[ni] = *reinterpret_cast<const v8s*>(W11 + (size_t)(wc * 128 + ni * 16 + q15) * 512 + k0);
#pragma unroll
        for (int mi = 0; mi < 2; ++mi)
#pragma unroll
            for (int ni = 0; ni < 8; ++ni)
                acc[mi][ni] = __builtin_amdgcn_mfma_f32_16x16x32_bf16(afr[mi], bfr[ni], acc[mi][ni], 0, 0, 0);
    }
#pragma unroll
    for (int ni = 0; ni < 8; ++ni) {
        const int col = wc * 128 + ni * 16 + q15;
        const float sc = fg[col] * rsqrtf(fv[col] + 1e-3f);
        const float tc = fbe[col] - fm[col] * sc;
        const float bia = fb[col];
#pragma unroll
        for (int mi = 0; mi < 2; ++mi)
#pragma unroll
            for (int r = 0; r < 4; ++r) {
                const int row = bm + wr * 32 + mi * 16 + g * 4 + r;
                float z = fmaxf((acc[mi][ni][r] + bia) * sc + tc, 0.f);
                out[(size_t)row * CD + col] = z;
            }
    }
}

// ---------------- launcher ---------------------------------------------------
extern "C" void kernel_launch(void* const* d_in, const int* in_sizes, int n_in,
                              void* d_out, int out_size, void* d_ws, size_t ws_size,
                              hipStream_t stream) {
    const float* f_low   = (const float*)d_in[0];
    const float* f_high  = (const float*)d_in[1];
    const float* bott_W  = (const float*)d_in[2];
    const float* bott_b  = (const float*)d_in[3];
    const float* bott_g  = (const float*)d_in[4];
    const float* bott_be = (const float*)d_in[5];
    const float* bott_m  = (const float*)d_in[6];
    const float* bott_v  = (const float*)d_in[7];
    const float* qkv_W   = (const float*)d_in[8];
    const float* qkv_g   = (const float*)d_in[9];
    const float* qkv_be  = (const float*)d_in[10];
    const float* qkv_m   = (const float*)d_in[11];
    const float* qkv_v   = (const float*)d_in[12];
    const float* mlp_W   = (const float*)d_in[13];
    const float* mlp_g   = (const float*)d_in[14];
    const float* mlp_be  = (const float*)d_in[15];
    const float* mlp_m   = (const float*)d_in[16];
    const float* mlp_v   = (const float*)d_in[17];
    const float* fus_W   = (const float*)d_in[18];
    const float* fus_b   = (const float*)d_in[19];
    const float* fus_g   = (const float*)d_in[20];
    const float* fus_be  = (const float*)d_in[21];
    const float* fus_m   = (const float*)d_in[22];
    const float* fus_v   = (const float*)d_in[23];
    (void)in_sizes; (void)n_in; (void)out_size; (void)ws_size;

    char* ws = (char*)d_ws;
    const size_t MB = 1024 * 1024;
    float* xA = (float*)(ws);                       // 16.8 MB residual stream
    ubf*   o0 = (ubf*)  (ws + 17 * MB);             // 8.4 MB attn half0 partial
    ubf*   qB = (ubf*)  (ws + 26 * MB);             // 8.4 MB Q (pre-scaled)
    ubf*   kB = (ubf*)  (ws + 35 * MB);             // 8.4 MB K
    ubf*   vT = (ubf*)  (ws + 44 * MB);             // 8.4 MB V chunk-major
    ubf*   wT = (ubf*)  (ws + 53 * MB);             // 1.7 MB, 12 transposed weights
    ubf*   o1 = (ubf*)  (ws + 56 * MB);             // 8.4 MB attn half1 partial
    float* ml = (float*)(ws + 65 * MB);             // 512 KB (m,l) x 2 halves

    k_pre<<<dim3(4096 + 1536), dim3(256), 0, stream>>>(f_low, xA,
                                                       bott_W, qkv_W, mlp_W, fus_W, wT);

    k_kv<<<dim3(128, 4), dim3(256), 0, stream>>>(f_high, wT + (size_t)6 * 65536,
                                                 qkv_g, qkv_be, qkv_m, qkv_v, kB, vT);

    k_conv1<<<dim3(256), dim3(256), 0, stream>>>(xA, wT,
                                                 bott_b, bott_g, bott_be, bott_m, bott_v,
                                                 qkv_g, qkv_be, qkv_m, qkv_v, qB);

    k_attn<<<dim3(512), dim3(128), 0, stream>>>(qB, kB, vT, o0, o1, ml);

    k_tail<<<dim3(256), dim3(256), 0, stream>>>(o0, o1, ml, xA, wT,
                                                mlp_g, mlp_be, mlp_m, mlp_v,
                                                fus_b, fus_g, fus_be, fus_m, fus_v,
                                                (float*)d_out);
}

// Round 19
// 281.390 us; speedup vs baseline: 1.0385x; 1.0300x over previous
//
#include <hip/hip_runtime.h>
#include <cstdint>
#include <cstddef>

typedef float v4f __attribute__((ext_vector_type(4)));
typedef float v2f __attribute__((ext_vector_type(2)));
typedef float v16f __attribute__((ext_vector_type(16)));
typedef short v8s __attribute__((ext_vector_type(8)));
typedef unsigned short v4u __attribute__((ext_vector_type(4)));

typedef unsigned short ubf;   // raw bf16 bits

#define NPTS 16384
#define CD   256
#define NBAT 4
#define NPB  4096

__device__ __forceinline__ float bf2f(ubf u) {
    union { unsigned u; float f; } c; c.u = ((unsigned)u) << 16; return c.f;
}
__device__ __forceinline__ ubf f2bf(float f) {
    union { float f; unsigned u; } c; c.f = f;
    unsigned u = c.u;
    u += 0x7fffu + ((u >> 16) & 1u);           // round-nearest-even
    return (ubf)(u >> 16);
}

// -------- fused pre-pass: weight transpose (blocks >= 4096) + point attention
__global__ __launch_bounds__(256) void k_pre(
    const float* __restrict__ low, float* __restrict__ xout,
    const float* __restrict__ bott, const float* __restrict__ qkv,
    const float* __restrict__ mlp, const float* __restrict__ fus,
    ubf* __restrict__ wt) {
    const int bid = blockIdx.x;
    if (bid < 4096) {
        // ---- Point_Attentation ----
        const int lane = threadIdx.x & 63;
        const int row  = bid * 4 + (threadIdx.x >> 6);
        const float* p = low + (size_t)row * CD + lane * 4;
        v4f v = *reinterpret_cast<const v4f*>(p);
        float d[4];
        float s = v[0] + v[1] + v[2] + v[3];
#pragma unroll
        for (int o = 32; o >= 1; o >>= 1) s += __shfl_xor(s, o);
        const float mean = s * (1.0f / 256.0f);
        float ss = 0.f;
#pragma unroll
        for (int i = 0; i < 4; ++i) { d[i] = v[i] - mean; ss += d[i] * d[i]; }
#pragma unroll
        for (int o = 32; o >= 1; o >>= 1) ss += __shfl_xor(ss, o);
        const float var = ss * (1.0f / 4095.0f);    // reference: /(n-1), n=4096
        const float dn  = 1.0f / (4.0f * (var + 1e-5f));
        v4f o;
#pragma unroll
        for (int i = 0; i < 4; ++i) {
            const float e   = d[i] * d[i] * dn + 0.5f;
            const float sig = 1.0f / (1.0f + __expf(-e));
            o[i] = v[i] * (1.0f + sig);
        }
        *reinterpret_cast<v4f*>(xout + (size_t)row * CD + lane * 4) = o;
        return;
    }
    // ---- weight transpose+convert: W[K][256] f32 -> WT[256][K] bf16 ----
    const int bid2 = bid - 4096;
    const int z = bid2 >> 7, r = bid2 & 127;
    const float* src; int K; size_t doff;
    if (z < 6)       { src = bott + (size_t)z * 65536;       K = 256; doff = (size_t)z * 65536; }
    else if (z < 9)  { src = qkv  + (size_t)(z - 6) * 65536; K = 256; doff = (size_t)z * 65536; }
    else if (z < 11) { src = mlp  + (size_t)(z - 9) * 65536; K = 256; doff = (size_t)z * 65536; }
    else             { src = fus;                            K = 512; doff = (size_t)11 * 65536; }
    const int kt = (r >> 3) * 32, nt = (r & 7) * 32;
    if (kt >= K) return;
    __shared__ ubf tile[32][33];
    const int tx = threadIdx.x & 31, ty = threadIdx.x >> 5;   // 32 x 8
#pragma unroll
    for (int i = 0; i < 4; ++i)
        tile[ty * 4 + i][tx] = f2bf(src[(size_t)(kt + ty * 4 + i) * 256 + nt + tx]);
    __syncthreads();
    ubf* dst = wt + doff;
#pragma unroll
    for (int i = 0; i < 4; ++i)
        dst[(size_t)(nt + ty * 4 + i) * K + kt + tx] = tile[tx][ty * 4 + i];
}

// ------- fused conv1 (3 bottlenecks) + q-projection from the LDS tile --------
__global__ __launch_bounds__(256) void k_conv1(
    float* __restrict__ xA, const ubf* __restrict__ wT,
    const float* __restrict__ bb, const float* __restrict__ bg,
    const float* __restrict__ bbe, const float* __restrict__ bm_,
    const float* __restrict__ bv,
    const float* __restrict__ qg, const float* __restrict__ qbe,
    const float* __restrict__ qm, const float* __restrict__ qv,
    ubf* __restrict__ qB) {
    __shared__ __attribute__((aligned(16))) float xls[64 * 256];  // 64KB
    __shared__ __attribute__((aligned(16))) ubf   yls[64 * 256];  // 32KB

    const int lane = threadIdx.x & 63;
    const int w    = threadIdx.x >> 6;
    const int wr = w >> 1, wc = w & 1;
    const int q15 = lane & 15, g = lane >> 4;
    const int bm = blockIdx.x * 64;

    {
        float* xsrcb = xA + (size_t)bm * 256;
#pragma unroll
        for (int it = 0; it < 16; ++it) {
            const int L4 = (it * 256 + w * 64) * 4;      // wave-uniform f32 base
            const int Ll = L4 + lane * 4;
            const int row = Ll >> 8, col = (Ll & 255) ^ ((row & 7) << 3);
            __builtin_amdgcn_global_load_lds(
                (const __attribute__((address_space(1))) unsigned*)(xsrcb + row * 256 + col),
                (__attribute__((address_space(3))) unsigned*)(xls + L4), 16, 0, 0);
        }
    }
    __syncthreads();

    const int r0l = wr * 32 + q15;
#pragma unroll 1
    for (int s = 0; s < 3; ++s) {
        const ubf* W0 = wT + (size_t)(2 * s) * 65536;
        const ubf* W1 = wT + (size_t)(2 * s + 1) * 65536;

        v4f acc[2][8];
#pragma unroll
        for (int i = 0; i < 2; ++i)
#pragma unroll
            for (int j = 0; j < 8; ++j)
#pragma unroll
                for (int r = 0; r < 4; ++r) acc[i][j][r] = 0.f;
        for (int ks = 0; ks < 8; ++ks) {
            const int k0 = ks * 32 + g * 8;
            v8s afr[2], bfr[8];
#pragma unroll
            for (int mi = 0; mi < 2; ++mi) {
                const int row = r0l + mi * 16;
                const float* ap = &xls[row * 256 + (k0 ^ ((row & 7) << 3))];
                v4f a = *reinterpret_cast<const v4f*>(ap);
                v4f b = *reinterpret_cast<const v4f*>(ap + 4);
                v8s t;
#pragma unroll
                for (int j = 0; j < 4; ++j) { t[j] = (short)f2bf(a[j]); t[j + 4] = (short)f2bf(b[j]); }
                afr[mi] = t;
            }
#pragma unroll
            for (int ni = 0; ni < 8; ++ni)
                bfr[ni] = *reinterpret_cast<const v8s*>(W0 + (size_t)(wc * 128 + ni * 16 + q15) * 256 + k0);
#pragma unroll
            for (int mi = 0; mi < 2; ++mi)
#pragma unroll
                for (int ni = 0; ni < 8; ++ni)
                    acc[mi][ni] = __builtin_amdgcn_mfma_f32_16x16x32_bf16(afr[mi], bfr[ni], acc[mi][ni], 0, 0, 0);
        }
#pragma unroll
        for (int ni = 0; ni < 8; ++ni) {
            const int col = wc * 128 + ni * 16 + q15;
            const float sc  = bg[2 * s * 256 + col] * rsqrtf(bv[2 * s * 256 + col] + 1e-3f);
            const float tc  = bbe[2 * s * 256 + col] - bm_[2 * s * 256 + col] * sc;
            const float bia = bb[2 * s * 256 + col];
#pragma unroll
            for (int mi = 0; mi < 2; ++mi)
#pragma unroll
                for (int r = 0; r < 4; ++r) {
                    const int row = wr * 32 + mi * 16 + g * 4 + r;
                    float z = fmaxf((acc[mi][ni][r] + bia) * sc + tc, 0.f);
                    yls[row * 256 + (col ^ ((row & 7) << 3))] = f2bf(z);
                }
        }
        __syncthreads();

#pragma unroll
        for (int i = 0; i < 2; ++i)
#pragma unroll
            for (int j = 0; j < 8; ++j)
#pragma unroll
                for (int r = 0; r < 4; ++r) acc[i][j][r] = 0.f;
        for (int ks = 0; ks < 8; ++ks) {
            const int k0 = ks * 32 + g * 8;
            v8s afr[2], bfr[8];
#pragma unroll
            for (int mi = 0; mi < 2; ++mi) {
                const int row = r0l + mi * 16;
                afr[mi] = *reinterpret_cast<const v8s*>(&yls[row * 256 + (k0 ^ ((row & 7) << 3))]);
            }
#pragma unroll
            for (int ni = 0; ni < 8; ++ni)
                bfr[ni] = *reinterpret_cast<const v8s*>(W1 + (size_t)(wc * 128 + ni * 16 + q15) * 256 + k0);
#pragma unroll
            for (int mi = 0; mi < 2; ++mi)
#pragma unroll
                for (int ni = 0; ni < 8; ++ni)
                    acc[mi][ni] = __builtin_amdgcn_mfma_f32_16x16x32_bf16(afr[mi], bfr[ni], acc[mi][ni], 0, 0, 0);
        }
#pragma unroll
        for (int ni = 0; ni < 8; ++ni) {
            const int col = wc * 128 + ni * 16 + q15;
            const int c1 = (2 * s + 1) * 256 + col;
            const float sc  = bg[c1] * rsqrtf(bv[c1] + 1e-3f);
            const float tc  = bbe[c1] - bm_[c1] * sc;
            const float bia = bb[c1];
#pragma unroll
            for (int mi = 0; mi < 2; ++mi)
#pragma unroll
                for (int r = 0; r < 4; ++r) {
                    const int row = wr * 32 + mi * 16 + g * 4 + r;
                    float z = fmaxf((acc[mi][ni][r] + bia) * sc + tc, 0.f);
                    xls[row * 256 + (col ^ ((row & 7) << 3))] += z;
                }
        }
        __syncthreads();
    }

    // ---- write xls back to xA (undo swizzle) ----
    {
        float* xdstb = xA + (size_t)bm * 256;
#pragma unroll
        for (int it = 0; it < 16; ++it) {
            const int Ll = (it * 256 + threadIdx.x) * 4;
            const int row = Ll >> 8, cl = Ll & 255;
            const int gcol = cl ^ ((row & 7) << 3);
            *reinterpret_cast<v4f*>(xdstb + row * 256 + gcol) =
                *reinterpret_cast<const v4f*>(xls + Ll);
        }
    }

    // ---- q projection from the LDS-resident tile ----
    {
        const ubf* WQ = wT + (size_t)6 * 65536;
        v4f acc[2][8];
#pragma unroll
        for (int i = 0; i < 2; ++i)
#pragma unroll
            for (int j = 0; j < 8; ++j)
#pragma unroll
                for (int r = 0; r < 4; ++r) acc[i][j][r] = 0.f;
        for (int ks = 0; ks < 8; ++ks) {
            const int k0 = ks * 32 + g * 8;
            v8s afr[2], bfr[8];
#pragma unroll
            for (int mi = 0; mi < 2; ++mi) {
                const int row = r0l + mi * 16;
                const float* ap = &xls[row * 256 + (k0 ^ ((row & 7) << 3))];
                v4f a = *reinterpret_cast<const v4f*>(ap);
                v4f b = *reinterpret_cast<const v4f*>(ap + 4);
                v8s t;
#pragma unroll
                for (int j = 0; j < 4; ++j) { t[j] = (short)f2bf(a[j]); t[j + 4] = (short)f2bf(b[j]); }
                afr[mi] = t;
            }
#pragma unroll
            for (int ni = 0; ni < 8; ++ni)
                bfr[ni] = *reinterpret_cast<const v8s*>(WQ + (size_t)(wc * 128 + ni * 16 + q15) * 256 + k0);
#pragma unroll
            for (int mi = 0; mi < 2; ++mi)
#pragma unroll
                for (int ni = 0; ni < 8; ++ni)
                    acc[mi][ni] = __builtin_amdgcn_mfma_f32_16x16x32_bf16(afr[mi], bfr[ni], acc[mi][ni], 0, 0, 0);
        }
#pragma unroll
        for (int ni = 0; ni < 8; ++ni) {
            const int col = wc * 128 + ni * 16 + q15;
            const float sc = qg[col] * rsqrtf(qv[col] + 1e-3f);
            const float tc = qbe[col] - qm[col] * sc;
#pragma unroll
            for (int mi = 0; mi < 2; ++mi)
#pragma unroll
                for (int r = 0; r < 4; ++r) {
                    const int row = bm + wr * 32 + mi * 16 + g * 4 + r;
                    qB[(size_t)row * CD + col] = f2bf(acc[mi][ni][r] * sc + tc);
                }
        }
    }
}

// ---------------- K/V projection: one dispatch, 512 blocks -------------------
// V written CHUNK-MAJOR: vT[b][chunk=key>>5][c][key&31].
__global__ __launch_bounds__(256) void k_kv(
    const float* __restrict__ fh, const ubf* __restrict__ wTq,
    const float* __restrict__ qg, const float* __restrict__ qbe,
    const float* __restrict__ qm, const float* __restrict__ qv,
    ubf* __restrict__ kB, ubf* __restrict__ vT) {
    const int m = 1 + (blockIdx.y >> 1);         // 1=k, 2=v
    const ubf* WT = wTq + m * 65536;
    const float* gamma = qg + m * 256;
    const float* beta  = qbe + m * 256;
    const float* bmean = qm + m * 256;
    const float* bvar  = qv + m * 256;

    const int lane = threadIdx.x & 63;
    const int w    = threadIdx.x >> 6;
    const int wr = w >> 1, wc = w & 1;
    const int q15 = lane & 15, g = lane >> 4;
    const int bm = blockIdx.x * 128, bn = (blockIdx.y & 1) * 128;
    const int r0 = bm + wr * 64 + q15;
    const int c0 = bn + wc * 64 + q15;

    v4f acc[4][4];
#pragma unroll
    for (int i = 0; i < 4; ++i)
#pragma unroll
        for (int j = 0; j < 4; ++j)
#pragma unroll
            for (int r = 0; r < 4; ++r) acc[i][j][r] = 0.f;

    for (int ks = 0; ks < 8; ++ks) {
        const int k0 = ks * 32 + g * 8;
        v8s afr[4], bfr[4];
#pragma unroll
        for (int mi = 0; mi < 4; ++mi) {
            const float* ap = fh + (size_t)(r0 + mi * 16) * CD + k0;
            v4f a = *reinterpret_cast<const v4f*>(ap);
            v4f b = *reinterpret_cast<const v4f*>(ap + 4);
            v8s t;
#pragma unroll
            for (int j = 0; j < 4; ++j) { t[j] = (short)f2bf(a[j]); t[j + 4] = (short)f2bf(b[j]); }
            afr[mi] = t;
        }
#pragma unroll
        for (int ni = 0; ni < 4; ++ni)
            bfr[ni] = *reinterpret_cast<const v8s*>(WT + (size_t)(c0 + ni * 16) * 256 + k0);
#pragma unroll
        for (int mi = 0; mi < 4; ++mi)
#pragma unroll
            for (int ni = 0; ni < 4; ++ni)
                acc[mi][ni] = __builtin_amdgcn_mfma_f32_16x16x32_bf16(afr[mi], bfr[ni], acc[mi][ni], 0, 0, 0);
    }

#pragma unroll
    for (int ni = 0; ni < 4; ++ni) {
        const int col = c0 + ni * 16;
        const float sc = gamma[col] * rsqrtf(bvar[col] + 1e-3f);
        const float tc = beta[col] - bmean[col] * sc;
#pragma unroll
        for (int mi = 0; mi < 4; ++mi) {
            if (m == 2) {
                const int row0 = bm + wr * 64 + mi * 16 + g * 4;
                v4u pk;
#pragma unroll
                for (int r = 0; r < 4; ++r) pk[r] = f2bf(acc[mi][ni][r] * sc + tc);
                const int bb = row0 >> 12, key = row0 & 4095;
                const int ch = key >> 5, kin = key & 31;
                *reinterpret_cast<v4u*>(vT + (size_t)bb * (CD * NPB)
                                           + (size_t)ch * (CD * 32) + col * 32 + kin) = pk;
            } else {
#pragma unroll
                for (int r = 0; r < 4; ++r) {
                    const int row = bm + wr * 64 + mi * 16 + g * 4 + r;
                    kB[(size_t)row * CD + col] = f2bf(acc[mi][ni][r] * sc + tc);
                }
            }
        }
    }
}

// ---- async stages (128-thread block, 2 waves) -------------------------------
__device__ __forceinline__ void stage_k32(const ubf* __restrict__ kg,
                                          ubf* kd, int wave, int lane) {
#pragma unroll
    for (int it = 0; it < 8; ++it) {
        const int Lb = it * 1024 + wave * 512;
        const int L  = Lb + lane * 8;
        const int key = L >> 8, c8 = (L & 255) ^ ((key & 7) << 3);
        __builtin_amdgcn_global_load_lds(
            (const __attribute__((address_space(1))) unsigned*)(kg + key * CD + c8),
            (__attribute__((address_space(3))) unsigned*)(kd + Lb), 16, 0, 0);
    }
}
__device__ __forceinline__ void stage_v40(const ubf* __restrict__ vchunk,
                                          ubf* vd, int wave, int lane) {
#pragma unroll
    for (int it = 0; it < 10; ++it) {
        const int e0b = wave * 5120 + it * 512;      // wave-uniform elem base
        const int e0  = e0b + lane * 8;
        const int c   = e0 / 40;
        const int k0  = e0 - c * 40;                 // 0,8,16,24,32
        const ubf* src = (k0 < 32) ? (vchunk + c * 32 + k0) : vchunk;
        __builtin_amdgcn_global_load_lds(
            (const __attribute__((address_space(1))) unsigned*)src,
            (__attribute__((address_space(3))) unsigned*)(vd + e0b), 16, 0, 0);
    }
}

// ---------------- flash attention: 32x32x16, r15-exact schedule + numerics ---
// 512 blocks x 128 thr (2 waves x 32 q-rows). Keys [half*2048,+2048) in 64
// chunks of 32. LDS = K 16K + V 20K + P 5K = 41KB (2 blocks/CU).
// Schedule/chunk: QK -> barrier -> stage K(kc+1) -> softmax+PV -> barrier ->
// stage V(kc+1). Single QK accumulator chain, e-domain softmax (r15's exact
// measured-best form: 127us; r17 split-chain and r18 exp2-prescale both
// regressed to ~136).
__global__ __launch_bounds__(128, 1) void k_attn(const ubf* __restrict__ qb, const ubf* __restrict__ kb,
                                                 const ubf* __restrict__ vt,
                                                 ubf* __restrict__ o0, ubf* __restrict__ o1,
                                                 float* __restrict__ ml) {
    __shared__ __attribute__((aligned(16))) ubf kls[32 * 256];    // 16KB
    __shared__ __attribute__((aligned(16))) ubf vls[256 * 40];    // 20KB stride-40
    __shared__ __attribute__((aligned(16))) ubf pls[2 * 32 * 40]; // 5KB per-wave P

    const int raw = blockIdx.x;                  // XCD swizzle: xcd = (b<<1)|half
    const int xcd = raw & 7, qt = raw >> 3;      // qt 0..63
    const int b = xcd >> 1, half = xcd & 1;

    const int wave = threadIdx.x >> 6, lane = threadIdx.x & 63;
    const int q31 = lane & 31, h = lane >> 5;

    // Q fragments: qf[ks] = Q[q31][ks*16 + h*8 .. +8]  (B-operand of K@Q^T)
    const ubf* qrow = qb + ((size_t)(b * NPB + qt * 64 + wave * 32 + q31)) * CD + h * 8;
    v8s qf[16];
#pragma unroll
    for (int ks = 0; ks < 16; ++ks) qf[ks] = *reinterpret_cast<const v8s*>(qrow + ks * 16);

    v16f oacc[8];
#pragma unroll
    for (int t = 0; t < 8; ++t)
#pragma unroll
        for (int r = 0; r < 16; ++r) oacc[t][r] = 0.f;
    float m_run = -3.0e38f, l_run = 0.f;

    const ubf* kgb = kb + ((size_t)(b * NPB) + half * 2048) * CD;
    const ubf* vgb = vt + (size_t)b * (CD * NPB) + (size_t)(half * 64) * (CD * 32);
    ubf* pw = pls + wave * (32 * 40);

    stage_k32(kgb, kls, wave, lane);
    stage_v40(vgb, vls, wave, lane);
    __syncthreads();                             // chunk 0 ready

    for (int kc = 0; kc < 64; ++kc) {
        // S' = K_chunk @ Q^T : A-frag lane reads K[key=q31][ks*16 + h*8 ..]
        v16f sacc;
#pragma unroll
        for (int r = 0; r < 16; ++r) sacc[r] = 0.f;
#pragma unroll
        for (int ks = 0; ks < 16; ++ks) {
            v8s af = *reinterpret_cast<const v8s*>(
                &kls[q31 * 256 + ((ks * 16 + h * 8) ^ ((q31 & 7) << 3))]);
            sacc = __builtin_amdgcn_mfma_f32_32x32x16_bf16(af, qf[ks], sacc, 0, 0, 0);
        }

        __syncthreads();                         // kls reads done; V(kc) drained
        if (kc + 1 < 64)                         // K(kc+1) flies under softmax+PV
            stage_k32(kgb + (size_t)(kc + 1) * 32 * CD, kls, wave, lane);

        // online softmax with defer-rescale (THR=8); lane owns q=q31, 16 keys
        float mloc = -3.0e38f;
#pragma unroll
        for (int r = 0; r < 16; ++r) {
            float x = sacc[r] * 0.0625f;
            sacc[r] = x;
            mloc = fmaxf(mloc, x);
        }
        mloc = fmaxf(mloc, __shfl_xor(mloc, 32));
        if (!__all(mloc <= m_run + 8.0f)) {
            const float mnew  = fmaxf(m_run, mloc);
            const float alpha = __expf(m_run - mnew);
            l_run *= alpha;
#pragma unroll
            for (int t = 0; t < 8; ++t)
#pragma unroll
                for (int r = 0; r < 16; ++r) oacc[t][r] *= alpha;
            m_run = mnew;
        }
        float lloc = 0.f;
#pragma unroll
        for (int r = 0; r < 16; ++r) {
            float p = __expf(sacc[r] - m_run);
            sacc[r] = p;
            lloc += p;
        }
        lloc += __shfl_xor(lloc, 32);
        l_run += lloc;

        // P -> LDS (bf16 trunc): reg 4G+r holds key = r + 8G + 4h for q31
#pragma unroll
        for (int G = 0; G < 4; ++G) {
            unsigned u0, u1, u2, u3;
            { union { float f; unsigned u; } c; c.f = sacc[4 * G + 0]; u0 = c.u; }
            { union { float f; unsigned u; } c; c.f = sacc[4 * G + 1]; u1 = c.u; }
            { union { float f; unsigned u; } c; c.f = sacc[4 * G + 2]; u2 = c.u; }
            { union { float f; unsigned u; } c; c.f = sacc[4 * G + 3]; u3 = c.u; }
            unsigned p01 = (u0 >> 16) | (u1 & 0xFFFF0000u);
            unsigned p23 = (u2 >> 16) | (u3 & 0xFFFF0000u);
            const int e = q31 * 40 + 8 * G + 4 * h;
            *reinterpret_cast<unsigned*>(&pw[e])     = p01;
            *reinterpret_cast<unsigned*>(&pw[e + 2]) = p23;
        }
        // O[c][q] += V^T_chunk @ P : B-frag = P[kb + h*8 ..][q31]
        v8s pb0 = *reinterpret_cast<const v8s*>(&pw[q31 * 40 + 0  + 8 * h]);
        v8s pb1 = *reinterpret_cast<const v8s*>(&pw[q31 * 40 + 16 + 8 * h]);
#pragma unroll
        for (int t = 0; t < 8; ++t) {
            const int crow = (t * 32 + q31) * 40;
            v8s av0 = *reinterpret_cast<const v8s*>(&vls[crow + 0  + 8 * h]);
            oacc[t] = __builtin_amdgcn_mfma_f32_32x32x16_bf16(av0, pb0, oacc[t], 0, 0, 0);
            v8s av1 = *reinterpret_cast<const v8s*>(&vls[crow + 16 + 8 * h]);
            oacc[t] = __builtin_amdgcn_mfma_f32_32x32x16_bf16(av1, pb1, oacc[t], 0, 0, 0);
        }

        __syncthreads();                         // vls reads done; K(kc+1) drained
        if (kc + 1 < 64)                         // V(kc+1) flies under next QK
            stage_v40(vgb + (size_t)(kc + 1) * (CD * 32), vls, wave, lane);
    }

    // epilogue: unnormalized partial O (bf16) + per-row (m, l)
    const int grow = b * NPB + qt * 64 + wave * 32 + q31;
    ubf* aor = (half ? o1 : o0) + (size_t)grow * CD;
#pragma unroll
    for (int t = 0; t < 8; ++t)
#pragma unroll
        for (int G = 0; G < 4; ++G) {
            v4u pk;
#pragma unroll
            for (int r = 0; r < 4; ++r) pk[r] = f2bf(oacc[t][4 * G + r]);
            *reinterpret_cast<v4u*>(aor + t * 32 + 8 * G + 4 * h) = pk;
        }
    if (h == 0) {
        v2f d; d[0] = m_run; d[1] = l_run;
        *reinterpret_cast<v2f*>(ml + (size_t)(half * NPTS + grow) * 2) = d;
    }
}

// ---------------- fused tail: merge+mlp1 -> mlp2 -> fusion (K=512) -----------
__global__ __launch_bounds__(256) void k_tail(
    const ubf* __restrict__ o0, const ubf* __restrict__ o1, const float* __restrict__ ml,
    const float* __restrict__ xA, const ubf* __restrict__ wT,
    const float* __restrict__ mg, const float* __restrict__ mbe,
    const float* __restrict__ mm, const float* __restrict__ mv,
    const float* __restrict__ fb, const float* __restrict__ fg,
    const float* __restrict__ fbe, const float* __restrict__ fm,
    const float* __restrict__ fv, float* __restrict__ out) {
    __shared__ __attribute__((aligned(16))) ubf yls[64 * 256];   // 32KB

    const int lane = threadIdx.x & 63;
    const int w    = threadIdx.x >> 6;
    const int wr = w >> 1, wc = w & 1;
    const int q15 = lane & 15, g = lane >> 4;
    const int bm = blockIdx.x * 64;
    const int r0l = wr * 32 + q15;

    const ubf* W9  = wT + (size_t)9 * 65536;
    const ubf* W10 = wT + (size_t)10 * 65536;
    const ubf* W11 = wT + (size_t)11 * 65536;

    v4f acc[2][8];

    float a0[2], a1[2];
#pragma unroll
    for (int mi = 0; mi < 2; ++mi) {
        const int row = bm + r0l + mi * 16;
        const float m0 = ml[2 * row],          l0 = ml[2 * row + 1];
        const float m1 = ml[2 * (NPTS + row)], l1 = ml[2 * (NPTS + row) + 1];
        const float mx = fmaxf(m0, m1);
        const float w0 = __expf(m0 - mx), w1 = __expf(m1 - mx);
        const float inv = 1.0f / (w0 * l0 + w1 * l1);
        a0[mi] = w0 * inv; a1[mi] = w1 * inv;
    }
#pragma unroll
    for (int i = 0; i < 2; ++i)
#pragma unroll
        for (int j = 0; j < 8; ++j)
#pragma unroll
            for (int r = 0; r < 4; ++r) acc[i][j][r] = 0.f;
    for (int ks = 0; ks < 8; ++ks) {
        const int k0 = ks * 32 + g * 8;
        v8s afr[2], bfr[8];
#pragma unroll
        for (int mi = 0; mi < 2; ++mi) {
            const int row = bm + r0l + mi * 16;
            v8s u0 = *reinterpret_cast<const v8s*>(o0 + (size_t)row * CD + k0);
            v8s u1 = *reinterpret_cast<const v8s*>(o1 + (size_t)row * CD + k0);
            v8s t;
#pragma unroll
            for (int j = 0; j < 8; ++j)
                t[j] = (short)f2bf(a0[mi] * bf2f((ubf)u0[j]) + a1[mi] * bf2f((ubf)u1[j]));
            afr[mi] = t;
        }
#pragma unroll
        for (int ni = 0; ni < 8; ++ni)
            bfr[ni] = *reinterpret_cast<const v8s*>(W9 + (size_t)(wc * 128 + ni * 16 + q15) * 256 + k0);
#pragma unroll
        for (int mi = 0; mi < 2; ++mi)
#pragma unroll
            for (int ni = 0; ni < 8; ++ni)
                acc[mi][ni] = __builtin_amdgcn_mfma_f32_16x16x32_bf16(afr[mi], bfr[ni], acc[mi][ni], 0, 0, 0);
    }
#pragma unroll
    for (int ni = 0; ni < 8; ++ni) {
        const int col = wc * 128 + ni * 16 + q15;
        const float sc = mg[col] * rsqrtf(mv[col] + 1e-3f);
        const float tc = mbe[col] - mm[col] * sc;
#pragma unroll
        for (int mi = 0; mi < 2; ++mi)
#pragma unroll
            for (int r = 0; r < 4; ++r) {
                const int row = wr * 32 + mi * 16 + g * 4 + r;
                float z = fmaxf(acc[mi][ni][r] * sc + tc, 0.f);
                yls[row * 256 + (col ^ ((row & 7) << 3))] = f2bf(z);
            }
    }
    __syncthreads();

#pragma unroll
    for (int i = 0; i < 2; ++i)
#pragma unroll
        for (int j = 0; j < 8; ++j)
#pragma unroll
            for (int r = 0; r < 4; ++r) acc[i][j][r] = 0.f;
    for (int ks = 0; ks < 8; ++ks) {
        const int k0 = ks * 32 + g * 8;
        v8s afr[2], bfr[8];
#pragma unroll
        for (int mi = 0; mi < 2; ++mi) {
            const int row = r0l + mi * 16;
            afr[mi] = *reinterpret_cast<const v8s*>(&yls[row * 256 + (k0 ^ ((row & 7) << 3))]);
        }
#pragma unroll
        for (int ni = 0; ni < 8; ++ni)
            bfr[ni] = *reinterpret_cast<const v8s*>(W10 + (size_t)(wc * 128 + ni * 16 + q15) * 256 + k0);
#pragma unroll
        for (int mi = 0; mi < 2; ++mi)
#pragma unroll
            for (int ni = 0; ni < 8; ++ni)
                acc[mi][ni] = __builtin_amdgcn_mfma_f32_16x16x32_bf16(afr[mi], bfr[ni], acc[mi][ni], 0, 0, 0);
    }
    __syncthreads();
#pragma unroll
    for (int ni = 0; ni < 8; ++ni) {
        const int col = wc * 128 + ni * 16 + q15;
        const float sc = mg[256 + col] * rsqrtf(mv[256 + col] + 1e-3f);
        const float tc = mbe[256 + col] - mm[256 + col] * sc;
#pragma unroll
        for (int mi = 0; mi < 2; ++mi)
#pragma unroll
            for (int r = 0; r < 4; ++r) {
                const int row = wr * 32 + mi * 16 + g * 4 + r;
                float z = fmaxf(acc[mi][ni][r] * sc + tc, 0.f);
                yls[row * 256 + (col ^ ((row & 7) << 3))] = f2bf(z);
            }
    }
    __syncthreads();

#pragma unroll
    for (int i = 0; i < 2; ++i)
#pragma unroll
        for (int j = 0; j < 8; ++j)
#pragma unroll
            for (int r = 0; r < 4; ++r) acc[i][j][r] = 0.f;
    for (int ks = 0; ks < 16; ++ks) {
        const int k0 = ks * 32 + g * 8;
        v8s afr[2], bfr[8];
#pragma unroll
        for (int mi = 0; mi < 2; ++mi) {
            if (k0 < 256) {
                const float* ap = xA + (size_t)(bm + r0l + mi * 16) * CD + k0;
                v4f a = *reinterpret_cast<const v4f*>(ap);
                v4f b = *reinterpret_cast<const v4f*>(ap + 4);
                v8s t;
#pragma unroll
                for (int j = 0; j < 4; ++j) { t[j] = (short)f2bf(a[j]); t[j + 4] = (short)f2bf(b[j]); }
                afr[mi] = t;
            } else {
                const int row = r0l + mi * 16, kk = k0 - 256;
                afr[mi] = *reinterpret_cast<const v8s*>(&yls[row * 256 + (kk ^ ((row & 7) << 3))]);
            }
        }
#pragma unroll
        for (int ni = 0; ni < 8; ++ni)
            bfr[ni] = *reinterpret_cast<const v8s*>(W11 + (size_t)(wc * 128 + ni * 16 + q15) * 512 + k0);
#pragma unroll
        for (int mi = 0; mi < 2; ++mi)
#pragma unroll
            for (int ni = 0; ni < 8; ++ni)
                acc[mi][ni] = __builtin_amdgcn_mfma_f32_16x16x32_bf16(afr[mi], bfr[ni], acc[mi][ni], 0, 0, 0);
    }
#pragma unroll
    for (int ni = 0; ni < 8; ++ni) {
        const int col = wc * 128 + ni * 16 + q15;
        const float sc = fg[col] * rsqrtf(fv[col] + 1e-3f);
        const float tc = fbe[col] - fm[col] * sc;
        const float bia = fb[col];
#pragma unroll
        for (int mi = 0; mi < 2; ++mi)
#pragma unroll
            for (int r = 0; r < 4; ++r) {
                const int row = bm + wr * 32 + mi * 16 + g * 4 + r;
                float z = fmaxf((acc[mi][ni][r] + bia) * sc + tc, 0.f);
                out[(size_t)row * CD + col] = z;
            }
    }
}

// ---------------- launcher ---------------------------------------------------
extern "C" void kernel_launch(void* const* d_in, const int* in_sizes, int n_in,
                              void* d_out, int out_size, void* d_ws, size_t ws_size,
                              hipStream_t stream) {
    const float* f_low   = (const float*)d_in[0];
    const float* f_high  = (const float*)d_in[1];
    const float* bott_W  = (const float*)d_in[2];
    const float* bott_b  = (const float*)d_in[3];
    const float* bott_g  = (const float*)d_in[4];
    const float* bott_be = (const float*)d_in[5];
    const float* bott_m  = (const float*)d_in[6];
    const float* bott_v  = (const float*)d_in[7];
    const float* qkv_W   = (const float*)d_in[8];
    const float* qkv_g   = (const float*)d_in[9];
    const float* qkv_be  = (const float*)d_in[10];
    const float* qkv_m   = (const float*)d_in[11];
    const float* qkv_v   = (const float*)d_in[12];
    const float* mlp_W   = (const float*)d_in[13];
    const float* mlp_g   = (const float*)d_in[14];
    const float* mlp_be  = (const float*)d_in[15];
    const float* mlp_m   = (const float*)d_in[16];
    const float* mlp_v   = (const float*)d_in[17];
    const float* fus_W   = (const float*)d_in[18];
    const float* fus_b   = (const float*)d_in[19];
    const float* fus_g   = (const float*)d_in[20];
    const float* fus_be  = (const float*)d_in[21];
    const float* fus_m   = (const float*)d_in[22];
    const float* fus_v   = (const float*)d_in[23];
    (void)in_sizes; (void)n_in; (void)out_size; (void)ws_size;

    char* ws = (char*)d_ws;
    const size_t MB = 1024 * 1024;
    float* xA = (float*)(ws);                       // 16.8 MB residual stream
    ubf*   o0 = (ubf*)  (ws + 17 * MB);             // 8.4 MB attn half0 partial
    ubf*   qB = (ubf*)  (ws + 26 * MB);             // 8.4 MB Q
    ubf*   kB = (ubf*)  (ws + 35 * MB);             // 8.4 MB K
    ubf*   vT = (ubf*)  (ws + 44 * MB);             // 8.4 MB V chunk-major
    ubf*   wT = (ubf*)  (ws + 53 * MB);             // 1.7 MB, 12 transposed weights
    ubf*   o1 = (ubf*)  (ws + 56 * MB);             // 8.4 MB attn half1 partial
    float* ml = (float*)(ws + 65 * MB);             // 512 KB (m,l) x 2 halves

    k_pre<<<dim3(4096 + 1536), dim3(256), 0, stream>>>(f_low, xA,
                                                       bott_W, qkv_W, mlp_W, fus_W, wT);

    k_kv<<<dim3(128, 4), dim3(256), 0, stream>>>(f_high, wT + (size_t)6 * 65536,
                                                 qkv_g, qkv_be, qkv_m, qkv_v, kB, vT);

    k_conv1<<<dim3(256), dim3(256), 0, stream>>>(xA, wT,
                                                 bott_b, bott_g, bott_be, bott_m, bott_v,
                                                 qkv_g, qkv_be, qkv_m, qkv_v, qB);

    k_attn<<<dim3(512), dim3(128), 0, stream>>>(qB, kB, vT, o0, o1, ml);

    k_tail<<<dim3(256), dim3(256), 0, stream>>>(o0, o1, ml, xA, wT,
                                                mlp_g, mlp_be, mlp_m, mlp_v,
                                                fus_b, fus_g, fus_be, fus_m, fus_v,
                                                (float*)d_out);
}